// Round 1
// baseline (595.284 us; speedup 1.0000x reference)
//
#include <hip/hip_runtime.h>
#include <hip/hip_bf16.h>
#include <cstdint>

// Problem constants: W [N=1024, M=8192], x [B=8192, N=1024], b [1024]
// idx = 0..4095 (quantized cols), idx_comp = 4096..8191 (continuous cols)

using bf16x8 = __attribute__((ext_vector_type(8))) __bf16;
using f32x4  = __attribute__((ext_vector_type(4))) float;

typedef const __attribute__((address_space(1))) void g_void;
typedef __attribute__((address_space(3))) void l_void;

__device__ __forceinline__ void gload16(const void* g, void* l) {
  __builtin_amdgcn_global_load_lds((g_void*)g, (l_void*)l, 16, 0, 0);
}

__device__ __forceinline__ ushort f2bf(float f) {
  union { float f; unsigned u; } c; c.f = f;
  unsigned r = c.u + 0x7FFFu + ((c.u >> 16) & 1u);  // RNE truncate
  return (ushort)(r >> 16);
}
__device__ __forceinline__ float bf2f(ushort u) {
  union { unsigned u; float f; } c; c.u = ((unsigned)u) << 16;
  return c.f;
}

// ---------------- amax(|x|) ----------------
__global__ void amax_x_kernel(const float4* __restrict__ x, int n4,
                              unsigned* __restrict__ out_bits) {
  float m = 0.f;
  for (int i = blockIdx.x * blockDim.x + threadIdx.x; i < n4;
       i += gridDim.x * blockDim.x) {
    float4 v = x[i];
    m = fmaxf(m, fmaxf(fmaxf(fabsf(v.x), fabsf(v.y)),
                       fmaxf(fabsf(v.z), fabsf(v.w))));
  }
  #pragma unroll
  for (int off = 32; off > 0; off >>= 1) m = fmaxf(m, __shfl_down(m, off));
  __shared__ float wm[4];
  int lane = threadIdx.x & 63, wave = threadIdx.x >> 6;
  if (lane == 0) wm[wave] = m;
  __syncthreads();
  if (threadIdx.x == 0) {
    float r = fmaxf(fmaxf(wm[0], wm[1]), fmaxf(wm[2], wm[3]));
    atomicMax(out_bits, __float_as_uint(r));  // non-negative floats: bit order == value order
  }
}

// ---------------- xq (fake-quant int8) + xbf (plain bf16 cast) ----------------
__global__ void prep_x_kernel(const float4* __restrict__ x,
                              const unsigned* __restrict__ amax_bits,
                              ushort* __restrict__ xq, ushort* __restrict__ xbf,
                              int n4) {
  const float amax = fmaxf(__uint_as_float(*amax_bits), 1e-8f);
  const float scale = 127.f / amax;
  for (int i = blockIdx.x * blockDim.x + threadIdx.x; i < n4;
       i += gridDim.x * blockDim.x) {
    float4 v = x[i];
    ushort4 q, bv;
    q.x = f2bf(fminf(fmaxf(rintf(v.x * scale), -128.f), 127.f) / scale);
    q.y = f2bf(fminf(fmaxf(rintf(v.y * scale), -128.f), 127.f) / scale);
    q.z = f2bf(fminf(fmaxf(rintf(v.z * scale), -128.f), 127.f) / scale);
    q.w = f2bf(fminf(fmaxf(rintf(v.w * scale), -128.f), 127.f) / scale);
    bv.x = f2bf(v.x); bv.y = f2bf(v.y); bv.z = f2bf(v.z); bv.w = f2bf(v.w);
    ((ushort4*)xq)[i] = q;
    ((ushort4*)xbf)[i] = bv;
  }
}

// ---------------- Wprep [1024, 8192] bf16: cols<4096 quantized, rest cast ----------------
__global__ void prep_w_kernel(const float* __restrict__ W, ushort* __restrict__ Wp) {
  const int t = blockIdx.x * blockDim.x + threadIdx.x;
  const int NQ = 1024 * 128;  // quant blocks of 32 (row-major over W[:, :4096])
  if (t < NQ) {
    const int krow = t >> 7;
    const int m0 = (t & 127) * 32;
    const float* src = W + (size_t)krow * 8192 + m0;
    float w[32]; float amax = 0.f;
    #pragma unroll
    for (int i = 0; i < 32; ++i) { w[i] = src[i]; amax = fmaxf(amax, fabsf(w[i])); }
    const float scale = fmaxf(amax, 1e-8f);
    // top-2 |w| indices, ties -> lower index (matches lax.top_k)
    int i1 = -1, i2 = -1; float v1 = -1.f, v2 = -1.f;
    #pragma unroll
    for (int i = 0; i < 32; ++i) {
      float a = fabsf(w[i]);
      if (a > v1)      { v2 = v1; i2 = i1; v1 = a; i1 = i; }
      else if (a > v2) { v2 = a; i2 = i; }
    }
    ushort* dst = Wp + (size_t)krow * 8192 + m0;
    #pragma unroll
    for (int i = 0; i < 32; ++i) {
      float nb = w[i] / scale;
      float q;
      if (i == i1 || i == i2) {
        q = rintf(nb * 7.f) / 7.f;
      } else {
        float s = (nb > 0.f) ? 1.f : ((nb < 0.f) ? -1.f : 0.f);
        q = s * ((fabsf(nb) > 0.66f) ? 1.f : (1.f / 3.f));
      }
      dst[i] = f2bf(q * scale);
    }
  } else {
    const int u = t - NQ;  // cast W[:, 4096:]: 1024*4096 floats, 4 per thread
    if (u < 1024 * 1024) {
      const int krow = u >> 10;
      const int c4 = u & 1023;
      float4 v = *(const float4*)(W + (size_t)krow * 8192 + 4096 + c4 * 4);
      ushort4 o;
      o.x = f2bf(v.x); o.y = f2bf(v.y); o.z = f2bf(v.z); o.w = f2bf(v.w);
      *(ushort4*)(Wp + (size_t)krow * 8192 + 4096 + c4 * 4) = o;
    }
  }
}

// ---------------- transpose Wprep [1024,8192] -> WprepT [8192,1024] ----------------
__global__ void transpose_w_kernel(const ushort* __restrict__ src,
                                   ushort* __restrict__ dst) {
  __shared__ ushort tile[32][33];
  const int col0 = blockIdx.x * 32;   // 0..8191 in src cols
  const int row0 = blockIdx.y * 32;   // 0..1023 in src rows
  const int tx = threadIdx.x;         // 32
  const int ty = threadIdx.y;         // 8
  #pragma unroll
  for (int r = 0; r < 32; r += 8)
    tile[ty + r][tx] = src[(size_t)(row0 + ty + r) * 8192 + col0 + tx];
  __syncthreads();
  #pragma unroll
  for (int r = 0; r < 32; r += 8)
    dst[(size_t)(col0 + ty + r) * 1024 + row0 + tx] = tile[tx][ty + r];
}

// ---------------- GEMM1: Hcat[8192,8192] = [xq|xbf] @ Wprep, fused amax(|hidden_exp|) ----------------
// A: xq (bx<32) or xbf (bx>=32), [8192,1024]; B^T: WprepT [8192,1024].
__global__ __launch_bounds__(256, 2) void gemm1_kernel(
    const ushort* __restrict__ Aq, const ushort* __restrict__ Af,
    const ushort* __restrict__ BT, ushort* __restrict__ C,
    unsigned* __restrict__ amax_bits) {
  __shared__ __align__(16) ushort As[128 * 32];
  __shared__ __align__(16) ushort Bs[128 * 32];
  __shared__ float wredmax[4];

  const int bx = blockIdx.x, by = blockIdx.y;
  const int tid = threadIdx.x;
  const int lane = tid & 63, wave = tid >> 6;
  const int wm = (wave >> 1) << 6, wn = (wave & 1) << 6;
  const int l15 = lane & 15, quad = lane >> 4;

  const ushort* Abase = (bx < 32) ? Aq : Af;
  const ushort* Ag = Abase + (size_t)(by * 128 + (tid >> 2)) * 1024 + (tid & 3) * 8;
  const ushort* Bg = BT + (size_t)(bx * 128 + (tid >> 2)) * 1024 + (tid & 3) * 8;
  ushort* Asl = As + tid * 8;
  ushort* Bsl = Bs + tid * 8;

  f32x4 acc[4][4];
  #pragma unroll
  for (int i = 0; i < 4; ++i)
    #pragma unroll
    for (int j = 0; j < 4; ++j) acc[i][j] = (f32x4){0.f, 0.f, 0.f, 0.f};

  for (int k0 = 0; k0 < 1024; k0 += 32) {
    __syncthreads();
    gload16(Ag + k0, Asl);
    gload16(Ag + 64 * 1024 + k0, Asl + 64 * 32);
    gload16(Bg + k0, Bsl);
    gload16(Bg + 64 * 1024 + k0, Bsl + 64 * 32);
    __syncthreads();

    bf16x8 af[4], bfr[4];
    #pragma unroll
    for (int i = 0; i < 4; ++i)
      af[i] = *(const bf16x8*)&As[(wm + i * 16 + l15) * 32 + quad * 8];
    #pragma unroll
    for (int j = 0; j < 4; ++j)
      bfr[j] = *(const bf16x8*)&Bs[(wn + j * 16 + l15) * 32 + quad * 8];

    #pragma unroll
    for (int i = 0; i < 4; ++i)
      #pragma unroll
      for (int j = 0; j < 4; ++j)
        acc[i][j] = __builtin_amdgcn_mfma_f32_16x16x32_bf16(af[i], bfr[j], acc[i][j], 0, 0, 0);
  }

  const int row0 = by * 128 + wm + quad * 4;
  const int col0 = bx * 128 + wn + l15;
  float lmax = 0.f;
  #pragma unroll
  for (int i = 0; i < 4; ++i)
    #pragma unroll
    for (int j = 0; j < 4; ++j)
      #pragma unroll
      for (int r = 0; r < 4; ++r) {
        float v = acc[i][j][r];
        lmax = fmaxf(lmax, fabsf(v));
        C[(size_t)(row0 + i * 16 + r) * 8192 + (col0 + j * 16)] = f2bf(v);
      }

  if (bx < 32) {  // amax only over hidden_exp half
    #pragma unroll
    for (int off = 32; off > 0; off >>= 1)
      lmax = fmaxf(lmax, __shfl_down(lmax, off));
    if (lane == 0) wredmax[wave] = lmax;
    __syncthreads();
    if (tid == 0) {
      float m = fmaxf(fmaxf(wredmax[0], wredmax[1]), fmaxf(wredmax[2], wredmax[3]));
      atomicMax(amax_bits, __float_as_uint(m));
    }
  }
}

// ---------------- quantize Hcat[:, :4096] in place ----------------
__global__ void quant_h_kernel(ushort* __restrict__ H,
                               const unsigned* __restrict__ amax_bits) {
  const float amax = fmaxf(__uint_as_float(*amax_bits), 1e-8f);
  const float scale = 127.f / amax;
  const int n = 8192 * 4096 / 4;  // ushort4 chunks
  for (int i = blockIdx.x * blockDim.x + threadIdx.x; i < n;
       i += gridDim.x * blockDim.x) {
    int row = i >> 10;       // 1024 ushort4-chunks per row-half
    int c4 = i & 1023;
    ushort4* p = (ushort4*)(H + (size_t)row * 8192) + c4;
    ushort4 a = *p;
    a.x = f2bf(fminf(fmaxf(rintf(bf2f(a.x) * scale), -128.f), 127.f) / scale);
    a.y = f2bf(fminf(fmaxf(rintf(bf2f(a.y) * scale), -128.f), 127.f) / scale);
    a.z = f2bf(fminf(fmaxf(rintf(bf2f(a.z) * scale), -128.f), 127.f) / scale);
    a.w = f2bf(fminf(fmaxf(rintf(bf2f(a.w) * scale), -128.f), 127.f) / scale);
    *p = a;
  }
}

// ---------------- GEMM2: out[8192,1024] = relu(Hcat @ Wprep^T + b), fp32 out ----------------
// A: Hcat [8192,8192]; B^T: Wprep [1024,8192] (row n = output col, k along stored cols).
__global__ __launch_bounds__(256, 2) void gemm2_kernel(
    const ushort* __restrict__ A, const ushort* __restrict__ BT,
    const float* __restrict__ bias, float* __restrict__ out) {
  __shared__ __align__(16) ushort As[128 * 32];
  __shared__ __align__(16) ushort Bs[128 * 32];

  const int bx = blockIdx.x, by = blockIdx.y;  // bx: 0..7 col tiles, by: 0..63 row tiles
  const int tid = threadIdx.x;
  const int lane = tid & 63, wave = tid >> 6;
  const int wm = (wave >> 1) << 6, wn = (wave & 1) << 6;
  const int l15 = lane & 15, quad = lane >> 4;

  const ushort* Ag = A + (size_t)(by * 128 + (tid >> 2)) * 8192 + (tid & 3) * 8;
  const ushort* Bg = BT + (size_t)(bx * 128 + (tid >> 2)) * 8192 + (tid & 3) * 8;
  ushort* Asl = As + tid * 8;
  ushort* Bsl = Bs + tid * 8;

  f32x4 acc[4][4];
  #pragma unroll
  for (int i = 0; i < 4; ++i)
    #pragma unroll
    for (int j = 0; j < 4; ++j) acc[i][j] = (f32x4){0.f, 0.f, 0.f, 0.f};

  for (int k0 = 0; k0 < 8192; k0 += 32) {
    __syncthreads();
    gload16(Ag + k0, Asl);
    gload16(Ag + (size_t)64 * 8192 + k0, Asl + 64 * 32);
    gload16(Bg + k0, Bsl);
    gload16(Bg + (size_t)64 * 8192 + k0, Bsl + 64 * 32);
    __syncthreads();

    bf16x8 af[4], bfr[4];
    #pragma unroll
    for (int i = 0; i < 4; ++i)
      af[i] = *(const bf16x8*)&As[(wm + i * 16 + l15) * 32 + quad * 8];
    #pragma unroll
    for (int j = 0; j < 4; ++j)
      bfr[j] = *(const bf16x8*)&Bs[(wn + j * 16 + l15) * 32 + quad * 8];

    #pragma unroll
    for (int i = 0; i < 4; ++i)
      #pragma unroll
      for (int j = 0; j < 4; ++j)
        acc[i][j] = __builtin_amdgcn_mfma_f32_16x16x32_bf16(af[i], bfr[j], acc[i][j], 0, 0, 0);
  }

  const int row0 = by * 128 + wm + quad * 4;
  const int col0 = bx * 128 + wn + l15;
  #pragma unroll
  for (int i = 0; i < 4; ++i)
    #pragma unroll
    for (int j = 0; j < 4; ++j) {
      float bv = bias[col0 + j * 16];
      #pragma unroll
      for (int r = 0; r < 4; ++r) {
        float v = acc[i][j][r] + bv;
        v = fmaxf(v, 0.f);
        out[(size_t)(row0 + i * 16 + r) * 1024 + (col0 + j * 16)] = v;
      }
    }
}

extern "C" void kernel_launch(void* const* d_in, const int* in_sizes, int n_in,
                              void* d_out, int out_size, void* d_ws, size_t ws_size,
                              hipStream_t stream) {
  (void)in_sizes; (void)n_in; (void)out_size; (void)ws_size;
  const float* x = (const float*)d_in[0];   // [8192,1024]
  const float* W = (const float*)d_in[1];   // [1024,8192]
  const float* b = (const float*)d_in[2];   // [1024]

  char* ws = (char*)d_ws;
  unsigned* scal = (unsigned*)ws;                       // [0]=amax_x bits, [1]=amax_h bits
  ushort* xq   = (ushort*)(ws + 256);                   // 16 MB
  ushort* xbf  = xq  + (size_t)8192 * 1024;             // 16 MB
  ushort* Wp   = xbf + (size_t)8192 * 1024;             // 16 MB [1024,8192]
  ushort* WpT  = Wp  + (size_t)1024 * 8192;             // 16 MB [8192,1024]
  ushort* Hcat = WpT + (size_t)8192 * 1024;             // 128 MB [8192,8192]

  hipMemsetAsync(scal, 0, 256, stream);  // ws is re-poisoned 0xAA before every call
  amax_x_kernel<<<2048, 256, 0, stream>>>((const float4*)x, 8192 * 1024 / 4, scal);
  prep_x_kernel<<<2048, 256, 0, stream>>>((const float4*)x, scal, xq, xbf, 8192 * 1024 / 4);
  prep_w_kernel<<<(1024 * 128 + 1024 * 1024 + 255) / 256, 256, 0, stream>>>(W, Wp);
  transpose_w_kernel<<<dim3(256, 32), dim3(32, 8), 0, stream>>>(Wp, WpT);
  gemm1_kernel<<<dim3(64, 64), 256, 0, stream>>>(xq, xbf, WpT, Hcat, scal + 1);
  quant_h_kernel<<<2048, 256, 0, stream>>>(Hcat, scal + 1);
  gemm2_kernel<<<dim3(8, 64), 256, 0, stream>>>(Hcat, Wp, b, (float*)d_out);
}

// Round 2
// 501.623 us; speedup vs baseline: 1.1867x; 1.1867x over previous
//
#include <hip/hip_runtime.h>
#include <hip/hip_bf16.h>
#include <cstdint>

// Problem constants: W [N=1024, M=8192], x [B=8192, N=1024], b [1024]
// idx = 0..4095 (quantized cols), idx_comp = 4096..8191 (continuous cols)

using bf16x8 = __attribute__((ext_vector_type(8))) __bf16;
using f32x4  = __attribute__((ext_vector_type(4))) float;

typedef const __attribute__((address_space(1))) void g_void;
typedef __attribute__((address_space(3))) void l_void;

__device__ __forceinline__ void gload16(const void* g, void* l) {
  __builtin_amdgcn_global_load_lds((g_void*)g, (l_void*)l, 16, 0, 0);
}

__device__ __forceinline__ ushort f2bf(float f) {
  union { float f; unsigned u; } c; c.f = f;
  unsigned r = c.u + 0x7FFFu + ((c.u >> 16) & 1u);  // RNE truncate
  return (ushort)(r >> 16);
}
__device__ __forceinline__ float bf2f(ushort u) {
  union { unsigned u; float f; } c; c.u = ((unsigned)u) << 16;
  return c.f;
}

// ---------------- amax(|x|) ----------------
__global__ void amax_x_kernel(const float4* __restrict__ x, int n4,
                              unsigned* __restrict__ out_bits) {
  float m = 0.f;
  for (int i = blockIdx.x * blockDim.x + threadIdx.x; i < n4;
       i += gridDim.x * blockDim.x) {
    float4 v = x[i];
    m = fmaxf(m, fmaxf(fmaxf(fabsf(v.x), fabsf(v.y)),
                       fmaxf(fabsf(v.z), fabsf(v.w))));
  }
  #pragma unroll
  for (int off = 32; off > 0; off >>= 1) m = fmaxf(m, __shfl_down(m, off));
  __shared__ float wm[4];
  int lane = threadIdx.x & 63, wave = threadIdx.x >> 6;
  if (lane == 0) wm[wave] = m;
  __syncthreads();
  if (threadIdx.x == 0) {
    float r = fmaxf(fmaxf(wm[0], wm[1]), fmaxf(wm[2], wm[3]));
    atomicMax(out_bits, __float_as_uint(r));  // non-negative floats: bit order == value order
  }
}

// ---------------- xq (fake-quant int8) + xbf (plain bf16 cast) ----------------
__global__ void prep_x_kernel(const float4* __restrict__ x,
                              const unsigned* __restrict__ amax_bits,
                              ushort* __restrict__ xq, ushort* __restrict__ xbf,
                              int n4) {
  const float amax = fmaxf(__uint_as_float(*amax_bits), 1e-8f);
  const float scale = 127.f / amax;
  for (int i = blockIdx.x * blockDim.x + threadIdx.x; i < n4;
       i += gridDim.x * blockDim.x) {
    float4 v = x[i];
    ushort4 q, bv;
    q.x = f2bf(fminf(fmaxf(rintf(v.x * scale), -128.f), 127.f) / scale);
    q.y = f2bf(fminf(fmaxf(rintf(v.y * scale), -128.f), 127.f) / scale);
    q.z = f2bf(fminf(fmaxf(rintf(v.z * scale), -128.f), 127.f) / scale);
    q.w = f2bf(fminf(fmaxf(rintf(v.w * scale), -128.f), 127.f) / scale);
    bv.x = f2bf(v.x); bv.y = f2bf(v.y); bv.z = f2bf(v.z); bv.w = f2bf(v.w);
    ((ushort4*)xq)[i] = q;
    ((ushort4*)xbf)[i] = bv;
  }
}

// ---------------- Wprep [1024, 8192] bf16: cols<4096 quantized, rest cast ----------------
__global__ void prep_w_kernel(const float* __restrict__ W, ushort* __restrict__ Wp) {
  const int t = blockIdx.x * blockDim.x + threadIdx.x;
  const int NQ = 1024 * 128;  // quant blocks of 32 (row-major over W[:, :4096])
  if (t < NQ) {
    const int krow = t >> 7;
    const int m0 = (t & 127) * 32;
    const float* src = W + (size_t)krow * 8192 + m0;
    float w[32]; float amax = 0.f;
    #pragma unroll
    for (int i = 0; i < 32; ++i) { w[i] = src[i]; amax = fmaxf(amax, fabsf(w[i])); }
    const float scale = fmaxf(amax, 1e-8f);
    // top-2 |w| indices, ties -> lower index (matches lax.top_k)
    int i1 = -1, i2 = -1; float v1 = -1.f, v2 = -1.f;
    #pragma unroll
    for (int i = 0; i < 32; ++i) {
      float a = fabsf(w[i]);
      if (a > v1)      { v2 = v1; i2 = i1; v1 = a; i1 = i; }
      else if (a > v2) { v2 = a; i2 = i; }
    }
    ushort* dst = Wp + (size_t)krow * 8192 + m0;
    #pragma unroll
    for (int i = 0; i < 32; ++i) {
      float nb = w[i] / scale;
      float q;
      if (i == i1 || i == i2) {
        q = rintf(nb * 7.f) / 7.f;
      } else {
        float s = (nb > 0.f) ? 1.f : ((nb < 0.f) ? -1.f : 0.f);
        q = s * ((fabsf(nb) > 0.66f) ? 1.f : (1.f / 3.f));
      }
      dst[i] = f2bf(q * scale);
    }
  } else {
    const int u = t - NQ;  // cast W[:, 4096:]: 1024*4096 floats, 4 per thread
    if (u < 1024 * 1024) {
      const int krow = u >> 10;
      const int c4 = u & 1023;
      float4 v = *(const float4*)(W + (size_t)krow * 8192 + 4096 + c4 * 4);
      ushort4 o;
      o.x = f2bf(v.x); o.y = f2bf(v.y); o.z = f2bf(v.z); o.w = f2bf(v.w);
      *(ushort4*)(Wp + (size_t)krow * 8192 + 4096 + c4 * 4) = o;
    }
  }
}

// ---------------- transpose Wprep [1024,8192] -> WprepT [8192,1024] ----------------
__global__ void transpose_w_kernel(const ushort* __restrict__ src,
                                   ushort* __restrict__ dst) {
  __shared__ ushort tile[32][33];
  const int col0 = blockIdx.x * 32;   // 0..8191 in src cols
  const int row0 = blockIdx.y * 32;   // 0..1023 in src rows
  const int tx = threadIdx.x;         // 32
  const int ty = threadIdx.y;         // 8
  #pragma unroll
  for (int r = 0; r < 32; r += 8)
    tile[ty + r][tx] = src[(size_t)(row0 + ty + r) * 8192 + col0 + tx];
  __syncthreads();
  #pragma unroll
  for (int r = 0; r < 32; r += 8)
    dst[(size_t)(col0 + ty + r) * 1024 + row0 + tx] = tile[tx][ty + r];
}

// ---------------- GEMM1: Hcat[8192,8192] = [xq|xbf] @ Wprep, fused amax(|hidden_exp|) ----------------
// A: xq (bx<32) or xbf (bx>=32), [8192,1024]; B^T: WprepT [8192,1024].
// 1-D grid of 4096 blocks; XCD-aware swizzle: xcd = l%8 owns supertile rows.
__global__ __launch_bounds__(256, 2) void gemm1_kernel(
    const ushort* __restrict__ Aq, const ushort* __restrict__ Af,
    const ushort* __restrict__ BT, ushort* __restrict__ C,
    unsigned* __restrict__ amax_bits) {
  __shared__ __align__(16) ushort As[128 * 32];
  __shared__ __align__(16) ushort Bs[128 * 32];
  __shared__ float wredmax[4];

  // XCD swizzle: l%8 = XCD (round-robin dispatch). Each XCD sweeps 8x8 block
  // supertiles so its resident 64 blocks share 8 A-tiles + 8 B-tiles in L2.
  const int l = blockIdx.x;
  const int xcd = l & 7;
  const int s = l >> 3;            // 0..511
  const int t = (xcd << 3) | (s >> 6);  // supertile 0..63
  const int u = s & 63;
  const int bx = ((t & 7) << 3) | (u & 7);   // 0..63
  const int by = ((t >> 3) << 3) | (u >> 3); // 0..63

  const int tid = threadIdx.x;
  const int lane = tid & 63, wave = tid >> 6;
  const int wm = (wave >> 1) << 6, wn = (wave & 1) << 6;
  const int l15 = lane & 15, quad = lane >> 4;

  const ushort* Abase = (bx < 32) ? Aq : Af;
  const ushort* Ag = Abase + (size_t)(by * 128 + (tid >> 2)) * 1024 + (tid & 3) * 8;
  const ushort* Bg = BT + (size_t)(bx * 128 + (tid >> 2)) * 1024 + (tid & 3) * 8;
  ushort* Asl = As + tid * 8;
  ushort* Bsl = Bs + tid * 8;

  f32x4 acc[4][4];
  #pragma unroll
  for (int i = 0; i < 4; ++i)
    #pragma unroll
    for (int j = 0; j < 4; ++j) acc[i][j] = (f32x4){0.f, 0.f, 0.f, 0.f};

  for (int k0 = 0; k0 < 1024; k0 += 32) {
    __syncthreads();
    gload16(Ag + k0, Asl);
    gload16(Ag + 64 * 1024 + k0, Asl + 64 * 32);
    gload16(Bg + k0, Bsl);
    gload16(Bg + 64 * 1024 + k0, Bsl + 64 * 32);
    __syncthreads();

    bf16x8 af[4], bfr[4];
    #pragma unroll
    for (int i = 0; i < 4; ++i)
      af[i] = *(const bf16x8*)&As[(wm + i * 16 + l15) * 32 + quad * 8];
    #pragma unroll
    for (int j = 0; j < 4; ++j)
      bfr[j] = *(const bf16x8*)&Bs[(wn + j * 16 + l15) * 32 + quad * 8];

    #pragma unroll
    for (int i = 0; i < 4; ++i)
      #pragma unroll
      for (int j = 0; j < 4; ++j)
        acc[i][j] = __builtin_amdgcn_mfma_f32_16x16x32_bf16(af[i], bfr[j], acc[i][j], 0, 0, 0);
  }

  const int row0 = by * 128 + wm + quad * 4;
  const int col0 = bx * 128 + wn + l15;
  float lmax = 0.f;
  #pragma unroll
  for (int i = 0; i < 4; ++i)
    #pragma unroll
    for (int j = 0; j < 4; ++j)
      #pragma unroll
      for (int r = 0; r < 4; ++r) {
        float v = acc[i][j][r];
        lmax = fmaxf(lmax, fabsf(v));
        C[(size_t)(row0 + i * 16 + r) * 8192 + (col0 + j * 16)] = f2bf(v);
      }

  if (bx < 32) {  // amax only over hidden_exp half
    #pragma unroll
    for (int off = 32; off > 0; off >>= 1)
      lmax = fmaxf(lmax, __shfl_down(lmax, off));
    if (lane == 0) wredmax[wave] = lmax;
    __syncthreads();
    if (tid == 0) {
      float m = fmaxf(fmaxf(wredmax[0], wredmax[1]), fmaxf(wredmax[2], wredmax[3]));
      atomicMax(amax_bits, __float_as_uint(m));
    }
  }
}

// ---------------- quantize Hcat[:, :4096] in place ----------------
__global__ void quant_h_kernel(ushort* __restrict__ H,
                               const unsigned* __restrict__ amax_bits) {
  const float amax = fmaxf(__uint_as_float(*amax_bits), 1e-8f);
  const float scale = 127.f / amax;
  const int n = 8192 * 4096 / 4;  // ushort4 chunks
  for (int i = blockIdx.x * blockDim.x + threadIdx.x; i < n;
       i += gridDim.x * blockDim.x) {
    int row = i >> 10;       // 1024 ushort4-chunks per row-half
    int c4 = i & 1023;
    ushort4* p = (ushort4*)(H + (size_t)row * 8192) + c4;
    ushort4 a = *p;
    a.x = f2bf(fminf(fmaxf(rintf(bf2f(a.x) * scale), -128.f), 127.f) / scale);
    a.y = f2bf(fminf(fmaxf(rintf(bf2f(a.y) * scale), -128.f), 127.f) / scale);
    a.z = f2bf(fminf(fmaxf(rintf(bf2f(a.z) * scale), -128.f), 127.f) / scale);
    a.w = f2bf(fminf(fmaxf(rintf(bf2f(a.w) * scale), -128.f), 127.f) / scale);
    *p = a;
  }
}

// ---------------- GEMM2: out[8192,1024] = relu(Hcat @ Wprep^T + b), fp32 out ----------------
// A: Hcat [8192,8192]; B^T: Wprep [1024,8192] (row n = output col, k along stored cols).
// 1-D grid of 512 blocks (all co-resident at 2 blocks/CU); XCD swizzle: each
// XCD owns 8 consecutive by row-tiles and sweeps all 8 bx for them, so each
// 2 MB A row-tile is fetched into exactly one XCD's L2.
__global__ __launch_bounds__(256, 2) void gemm2_kernel(
    const ushort* __restrict__ A, const ushort* __restrict__ BT,
    const float* __restrict__ bias, float* __restrict__ out) {
  __shared__ __align__(16) ushort As[128 * 32];
  __shared__ __align__(16) ushort Bs[128 * 32];

  const int l = blockIdx.x;
  const int xcd = l & 7;
  const int s = l >> 3;                 // 0..63
  const int by = (xcd << 3) | (s >> 3); // 0..63
  const int bx = s & 7;                 // 0..7

  const int tid = threadIdx.x;
  const int lane = tid & 63, wave = tid >> 6;
  const int wm = (wave >> 1) << 6, wn = (wave & 1) << 6;
  const int l15 = lane & 15, quad = lane >> 4;

  const ushort* Ag = A + (size_t)(by * 128 + (tid >> 2)) * 8192 + (tid & 3) * 8;
  const ushort* Bg = BT + (size_t)(bx * 128 + (tid >> 2)) * 8192 + (tid & 3) * 8;
  ushort* Asl = As + tid * 8;
  ushort* Bsl = Bs + tid * 8;

  f32x4 acc[4][4];
  #pragma unroll
  for (int i = 0; i < 4; ++i)
    #pragma unroll
    for (int j = 0; j < 4; ++j) acc[i][j] = (f32x4){0.f, 0.f, 0.f, 0.f};

  for (int k0 = 0; k0 < 8192; k0 += 32) {
    __syncthreads();
    gload16(Ag + k0, Asl);
    gload16(Ag + (size_t)64 * 8192 + k0, Asl + 64 * 32);
    gload16(Bg + k0, Bsl);
    gload16(Bg + (size_t)64 * 8192 + k0, Bsl + 64 * 32);
    __syncthreads();

    bf16x8 af[4], bfr[4];
    #pragma unroll
    for (int i = 0; i < 4; ++i)
      af[i] = *(const bf16x8*)&As[(wm + i * 16 + l15) * 32 + quad * 8];
    #pragma unroll
    for (int j = 0; j < 4; ++j)
      bfr[j] = *(const bf16x8*)&Bs[(wn + j * 16 + l15) * 32 + quad * 8];

    #pragma unroll
    for (int i = 0; i < 4; ++i)
      #pragma unroll
      for (int j = 0; j < 4; ++j)
        acc[i][j] = __builtin_amdgcn_mfma_f32_16x16x32_bf16(af[i], bfr[j], acc[i][j], 0, 0, 0);
  }

  const int row0 = by * 128 + wm + quad * 4;
  const int col0 = bx * 128 + wn + l15;
  #pragma unroll
  for (int i = 0; i < 4; ++i)
    #pragma unroll
    for (int j = 0; j < 4; ++j) {
      float bv = bias[col0 + j * 16];
      #pragma unroll
      for (int r = 0; r < 4; ++r) {
        float v = acc[i][j][r] + bv;
        v = fmaxf(v, 0.f);
        out[(size_t)(row0 + i * 16 + r) * 1024 + (col0 + j * 16)] = v;
      }
    }
}

extern "C" void kernel_launch(void* const* d_in, const int* in_sizes, int n_in,
                              void* d_out, int out_size, void* d_ws, size_t ws_size,
                              hipStream_t stream) {
  (void)in_sizes; (void)n_in; (void)out_size; (void)ws_size;
  const float* x = (const float*)d_in[0];   // [8192,1024]
  const float* W = (const float*)d_in[1];   // [1024,8192]
  const float* b = (const float*)d_in[2];   // [1024]

  char* ws = (char*)d_ws;
  unsigned* scal = (unsigned*)ws;                       // [0]=amax_x bits, [1]=amax_h bits
  ushort* xq   = (ushort*)(ws + 256);                   // 16 MB
  ushort* xbf  = xq  + (size_t)8192 * 1024;             // 16 MB
  ushort* Wp   = xbf + (size_t)8192 * 1024;             // 16 MB [1024,8192]
  ushort* WpT  = Wp  + (size_t)1024 * 8192;             // 16 MB [8192,1024]
  ushort* Hcat = WpT + (size_t)8192 * 1024;             // 128 MB [8192,8192]

  hipMemsetAsync(scal, 0, 256, stream);  // ws is re-poisoned 0xAA before every call
  amax_x_kernel<<<2048, 256, 0, stream>>>((const float4*)x, 8192 * 1024 / 4, scal);
  prep_x_kernel<<<2048, 256, 0, stream>>>((const float4*)x, scal, xq, xbf, 8192 * 1024 / 4);
  prep_w_kernel<<<(1024 * 128 + 1024 * 1024 + 255) / 256, 256, 0, stream>>>(W, Wp);
  transpose_w_kernel<<<dim3(256, 32), dim3(32, 8), 0, stream>>>(Wp, WpT);
  gemm1_kernel<<<4096, 256, 0, stream>>>(xq, xbf, WpT, Hcat, scal + 1);
  quant_h_kernel<<<2048, 256, 0, stream>>>(Hcat, scal + 1);
  gemm2_kernel<<<512, 256, 0, stream>>>(Hcat, Wp, b, (float*)d_out);
}

// Round 3
// 469.049 us; speedup vs baseline: 1.2691x; 1.0694x over previous
//
#include <hip/hip_runtime.h>
#include <hip/hip_bf16.h>
#include <cstdint>

// Problem constants: W [N=1024, M=8192], x [B=8192, N=1024], b [1024]
// idx = 0..4095 (quantized cols), idx_comp = 4096..8191 (continuous cols)

using bf16x8 = __attribute__((ext_vector_type(8))) __bf16;
using f32x4  = __attribute__((ext_vector_type(4))) float;

typedef const __attribute__((address_space(1))) void g_void;
typedef __attribute__((address_space(3))) void l_void;

__device__ __forceinline__ void gload16(const void* g, void* l) {
  __builtin_amdgcn_global_load_lds((g_void*)g, (l_void*)l, 16, 0, 0);
}

__device__ __forceinline__ ushort f2bf(float f) {
  union { float f; unsigned u; } c; c.f = f;
  unsigned r = c.u + 0x7FFFu + ((c.u >> 16) & 1u);  // RNE truncate
  return (ushort)(r >> 16);
}
__device__ __forceinline__ float bf2f(ushort u) {
  union { unsigned u; float f; } c; c.u = ((unsigned)u) << 16;
  return c.f;
}

// ---------------- amax(|x|) ----------------
__global__ void amax_x_kernel(const float4* __restrict__ x, int n4,
                              unsigned* __restrict__ out_bits) {
  float m = 0.f;
  for (int i = blockIdx.x * blockDim.x + threadIdx.x; i < n4;
       i += gridDim.x * blockDim.x) {
    float4 v = x[i];
    m = fmaxf(m, fmaxf(fmaxf(fabsf(v.x), fabsf(v.y)),
                       fmaxf(fabsf(v.z), fabsf(v.w))));
  }
  #pragma unroll
  for (int off = 32; off > 0; off >>= 1) m = fmaxf(m, __shfl_down(m, off));
  __shared__ float wm[4];
  int lane = threadIdx.x & 63, wave = threadIdx.x >> 6;
  if (lane == 0) wm[wave] = m;
  __syncthreads();
  if (threadIdx.x == 0) {
    float r = fmaxf(fmaxf(wm[0], wm[1]), fmaxf(wm[2], wm[3]));
    atomicMax(out_bits, __float_as_uint(r));  // non-negative floats: bit order == value order
  }
}

// ---------------- xq (fake-quant int8) + xbf (plain bf16 cast) ----------------
__global__ void prep_x_kernel(const float4* __restrict__ x,
                              const unsigned* __restrict__ amax_bits,
                              ushort* __restrict__ xq, ushort* __restrict__ xbf,
                              int n4) {
  const float amax = fmaxf(__uint_as_float(*amax_bits), 1e-8f);
  const float scale = 127.f / amax;
  for (int i = blockIdx.x * blockDim.x + threadIdx.x; i < n4;
       i += gridDim.x * blockDim.x) {
    float4 v = x[i];
    ushort4 q, bv;
    q.x = f2bf(fminf(fmaxf(rintf(v.x * scale), -128.f), 127.f) / scale);
    q.y = f2bf(fminf(fmaxf(rintf(v.y * scale), -128.f), 127.f) / scale);
    q.z = f2bf(fminf(fmaxf(rintf(v.z * scale), -128.f), 127.f) / scale);
    q.w = f2bf(fminf(fmaxf(rintf(v.w * scale), -128.f), 127.f) / scale);
    bv.x = f2bf(v.x); bv.y = f2bf(v.y); bv.z = f2bf(v.z); bv.w = f2bf(v.w);
    ((ushort4*)xq)[i] = q;
    ((ushort4*)xbf)[i] = bv;
  }
}

// ---------------- Wprep [1024, 8192] bf16: cols<4096 quantized, rest cast ----------------
__global__ void prep_w_kernel(const float* __restrict__ W, ushort* __restrict__ Wp) {
  const int t = blockIdx.x * blockDim.x + threadIdx.x;
  const int NQ = 1024 * 128;  // quant blocks of 32 (row-major over W[:, :4096])
  if (t < NQ) {
    const int krow = t >> 7;
    const int m0 = (t & 127) * 32;
    const float* src = W + (size_t)krow * 8192 + m0;
    float w[32]; float amax = 0.f;
    #pragma unroll
    for (int i = 0; i < 32; ++i) { w[i] = src[i]; amax = fmaxf(amax, fabsf(w[i])); }
    const float scale = fmaxf(amax, 1e-8f);
    // top-2 |w| indices, ties -> lower index (matches lax.top_k)
    int i1 = -1, i2 = -1; float v1 = -1.f, v2 = -1.f;
    #pragma unroll
    for (int i = 0; i < 32; ++i) {
      float a = fabsf(w[i]);
      if (a > v1)      { v2 = v1; i2 = i1; v1 = a; i1 = i; }
      else if (a > v2) { v2 = a; i2 = i; }
    }
    ushort* dst = Wp + (size_t)krow * 8192 + m0;
    #pragma unroll
    for (int i = 0; i < 32; ++i) {
      float nb = w[i] / scale;
      float q;
      if (i == i1 || i == i2) {
        q = rintf(nb * 7.f) / 7.f;
      } else {
        float s = (nb > 0.f) ? 1.f : ((nb < 0.f) ? -1.f : 0.f);
        q = s * ((fabsf(nb) > 0.66f) ? 1.f : (1.f / 3.f));
      }
      dst[i] = f2bf(q * scale);
    }
  } else {
    const int u = t - NQ;  // cast W[:, 4096:]: 1024*4096 floats, 4 per thread
    if (u < 1024 * 1024) {
      const int krow = u >> 10;
      const int c4 = u & 1023;
      float4 v = *(const float4*)(W + (size_t)krow * 8192 + 4096 + c4 * 4);
      ushort4 o;
      o.x = f2bf(v.x); o.y = f2bf(v.y); o.z = f2bf(v.z); o.w = f2bf(v.w);
      *(ushort4*)(Wp + (size_t)krow * 8192 + 4096 + c4 * 4) = o;
    }
  }
}

// ---------------- transpose Wprep [1024,8192] -> WprepT [8192,1024] ----------------
__global__ void transpose_w_kernel(const ushort* __restrict__ src,
                                   ushort* __restrict__ dst) {
  __shared__ ushort tile[32][33];
  const int col0 = blockIdx.x * 32;   // 0..8191 in src cols
  const int row0 = blockIdx.y * 32;   // 0..1023 in src rows
  const int tx = threadIdx.x;         // 32
  const int ty = threadIdx.y;         // 8
  #pragma unroll
  for (int r = 0; r < 32; r += 8)
    tile[ty + r][tx] = src[(size_t)(row0 + ty + r) * 8192 + col0 + tx];
  __syncthreads();
  #pragma unroll
  for (int r = 0; r < 32; r += 8)
    dst[(size_t)(col0 + ty + r) * 1024 + row0 + tx] = tile[tx][ty + r];
}

// ---------------- GEMM1: Hcat[8192,8192] = [xq|xbf] @ Wprep, fused amax(|hidden_exp|) ----------------
// A: xq (bx<32) or xbf (bx>=32), [8192,1024]; B^T: WprepT [8192,1024].
// BK=64 as two BK=32 panels: identical per-panel LDS layout to the proven
// m97 pattern (ds_read_b128 stride-64B, gload16 lane-contiguous), but one
// barrier-pair now covers 32 MFMAs instead of 16.
__global__ __launch_bounds__(256, 2) void gemm1_kernel(
    const ushort* __restrict__ Aq, const ushort* __restrict__ Af,
    const ushort* __restrict__ BT, ushort* __restrict__ C,
    unsigned* __restrict__ amax_bits) {
  __shared__ __align__(16) ushort As[2][128 * 32];
  __shared__ __align__(16) ushort Bs[2][128 * 32];
  __shared__ float wredmax[4];

  // XCD swizzle: l%8 = XCD (round-robin dispatch). Each XCD sweeps 8x8 block
  // supertiles so its resident blocks share A/B tiles in its L2.
  const int l = blockIdx.x;
  const int xcd = l & 7;
  const int s = l >> 3;            // 0..511
  const int t = (xcd << 3) | (s >> 6);  // supertile 0..63
  const int u = s & 63;
  const int bx = ((t & 7) << 3) | (u & 7);   // 0..63
  const int by = ((t >> 3) << 3) | (u >> 3); // 0..63

  const int tid = threadIdx.x;
  const int lane = tid & 63, wave = tid >> 6;
  const int wm = (wave >> 1) << 6, wn = (wave & 1) << 6;
  const int l15 = lane & 15, quad = lane >> 4;

  const ushort* Abase = (bx < 32) ? Aq : Af;
  const ushort* Ag = Abase + (size_t)(by * 128 + (tid >> 2)) * 1024 + (tid & 3) * 8;
  const ushort* Bg = BT + (size_t)(bx * 128 + (tid >> 2)) * 1024 + (tid & 3) * 8;
  ushort* Asl0 = As[0] + tid * 8;
  ushort* Asl1 = As[1] + tid * 8;
  ushort* Bsl0 = Bs[0] + tid * 8;
  ushort* Bsl1 = Bs[1] + tid * 8;

  f32x4 acc[4][4];
  #pragma unroll
  for (int i = 0; i < 4; ++i)
    #pragma unroll
    for (int j = 0; j < 4; ++j) acc[i][j] = (f32x4){0.f, 0.f, 0.f, 0.f};

  for (int k0 = 0; k0 < 1024; k0 += 64) {
    __syncthreads();
    gload16(Ag + k0, Asl0);
    gload16(Ag + 64 * 1024 + k0, Asl0 + 64 * 32);
    gload16(Bg + k0, Bsl0);
    gload16(Bg + 64 * 1024 + k0, Bsl0 + 64 * 32);
    gload16(Ag + k0 + 32, Asl1);
    gload16(Ag + 64 * 1024 + k0 + 32, Asl1 + 64 * 32);
    gload16(Bg + k0 + 32, Bsl1);
    gload16(Bg + 64 * 1024 + k0 + 32, Bsl1 + 64 * 32);
    __syncthreads();

    #pragma unroll
    for (int p = 0; p < 2; ++p) {
      bf16x8 af[4], bfr[4];
      #pragma unroll
      for (int i = 0; i < 4; ++i)
        af[i] = *(const bf16x8*)&As[p][(wm + i * 16 + l15) * 32 + quad * 8];
      #pragma unroll
      for (int j = 0; j < 4; ++j)
        bfr[j] = *(const bf16x8*)&Bs[p][(wn + j * 16 + l15) * 32 + quad * 8];

      #pragma unroll
      for (int i = 0; i < 4; ++i)
        #pragma unroll
        for (int j = 0; j < 4; ++j)
          acc[i][j] = __builtin_amdgcn_mfma_f32_16x16x32_bf16(af[i], bfr[j], acc[i][j], 0, 0, 0);
    }
  }

  const int row0 = by * 128 + wm + quad * 4;
  const int col0 = bx * 128 + wn + l15;
  float lmax = 0.f;
  #pragma unroll
  for (int i = 0; i < 4; ++i)
    #pragma unroll
    for (int j = 0; j < 4; ++j)
      #pragma unroll
      for (int r = 0; r < 4; ++r) {
        float v = acc[i][j][r];
        lmax = fmaxf(lmax, fabsf(v));
        C[(size_t)(row0 + i * 16 + r) * 8192 + (col0 + j * 16)] = f2bf(v);
      }

  if (bx < 32) {  // amax only over hidden_exp half
    #pragma unroll
    for (int off = 32; off > 0; off >>= 1)
      lmax = fmaxf(lmax, __shfl_down(lmax, off));
    if (lane == 0) wredmax[wave] = lmax;
    __syncthreads();
    if (tid == 0) {
      float m = fmaxf(fmaxf(wredmax[0], wredmax[1]), fmaxf(wredmax[2], wredmax[3]));
      atomicMax(amax_bits, __float_as_uint(m));
    }
  }
}

// ---------------- quantize Hcat[:, :4096] in place ----------------
__global__ void quant_h_kernel(ushort* __restrict__ H,
                               const unsigned* __restrict__ amax_bits) {
  const float amax = fmaxf(__uint_as_float(*amax_bits), 1e-8f);
  const float scale = 127.f / amax;
  const int n = 8192 * 4096 / 4;  // ushort4 chunks
  for (int i = blockIdx.x * blockDim.x + threadIdx.x; i < n;
       i += gridDim.x * blockDim.x) {
    int row = i >> 10;       // 1024 ushort4-chunks per row-half
    int c4 = i & 1023;
    ushort4* p = (ushort4*)(H + (size_t)row * 8192) + c4;
    ushort4 a = *p;
    a.x = f2bf(fminf(fmaxf(rintf(bf2f(a.x) * scale), -128.f), 127.f) / scale);
    a.y = f2bf(fminf(fmaxf(rintf(bf2f(a.y) * scale), -128.f), 127.f) / scale);
    a.z = f2bf(fminf(fmaxf(rintf(bf2f(a.z) * scale), -128.f), 127.f) / scale);
    a.w = f2bf(fminf(fmaxf(rintf(bf2f(a.w) * scale), -128.f), 127.f) / scale);
    *p = a;
  }
}

// ---------------- GEMM2: out[8192,1024] = relu(Hcat @ Wprep^T + b), fp32 out ----------------
// A: Hcat [8192,8192]; B^T: Wprep [1024,8192] (row n = output col, k along stored cols).
// 512 blocks, all co-resident; XCD swizzle: each XCD owns 8 consecutive by
// row-tiles and sweeps all 8 bx, so each 2 MB A row-panel lives in one L2.
__global__ __launch_bounds__(256, 2) void gemm2_kernel(
    const ushort* __restrict__ A, const ushort* __restrict__ BT,
    const float* __restrict__ bias, float* __restrict__ out) {
  __shared__ __align__(16) ushort As[2][128 * 32];
  __shared__ __align__(16) ushort Bs[2][128 * 32];

  const int l = blockIdx.x;
  const int xcd = l & 7;
  const int s = l >> 3;                 // 0..63
  const int by = (xcd << 3) | (s >> 3); // 0..63
  const int bx = s & 7;                 // 0..7

  const int tid = threadIdx.x;
  const int lane = tid & 63, wave = tid >> 6;
  const int wm = (wave >> 1) << 6, wn = (wave & 1) << 6;
  const int l15 = lane & 15, quad = lane >> 4;

  const ushort* Ag = A + (size_t)(by * 128 + (tid >> 2)) * 8192 + (tid & 3) * 8;
  const ushort* Bg = BT + (size_t)(bx * 128 + (tid >> 2)) * 8192 + (tid & 3) * 8;
  ushort* Asl0 = As[0] + tid * 8;
  ushort* Asl1 = As[1] + tid * 8;
  ushort* Bsl0 = Bs[0] + tid * 8;
  ushort* Bsl1 = Bs[1] + tid * 8;

  f32x4 acc[4][4];
  #pragma unroll
  for (int i = 0; i < 4; ++i)
    #pragma unroll
    for (int j = 0; j < 4; ++j) acc[i][j] = (f32x4){0.f, 0.f, 0.f, 0.f};

  for (int k0 = 0; k0 < 8192; k0 += 64) {
    __syncthreads();
    gload16(Ag + k0, Asl0);
    gload16(Ag + (size_t)64 * 8192 + k0, Asl0 + 64 * 32);
    gload16(Bg + k0, Bsl0);
    gload16(Bg + (size_t)64 * 8192 + k0, Bsl0 + 64 * 32);
    gload16(Ag + k0 + 32, Asl1);
    gload16(Ag + (size_t)64 * 8192 + k0 + 32, Asl1 + 64 * 32);
    gload16(Bg + k0 + 32, Bsl1);
    gload16(Bg + (size_t)64 * 8192 + k0 + 32, Bsl1 + 64 * 32);
    __syncthreads();

    #pragma unroll
    for (int p = 0; p < 2; ++p) {
      bf16x8 af[4], bfr[4];
      #pragma unroll
      for (int i = 0; i < 4; ++i)
        af[i] = *(const bf16x8*)&As[p][(wm + i * 16 + l15) * 32 + quad * 8];
      #pragma unroll
      for (int j = 0; j < 4; ++j)
        bfr[j] = *(const bf16x8*)&Bs[p][(wn + j * 16 + l15) * 32 + quad * 8];

      #pragma unroll
      for (int i = 0; i < 4; ++i)
        #pragma unroll
        for (int j = 0; j < 4; ++j)
          acc[i][j] = __builtin_amdgcn_mfma_f32_16x16x32_bf16(af[i], bfr[j], acc[i][j], 0, 0, 0);
    }
  }

  const int row0 = by * 128 + wm + quad * 4;
  const int col0 = bx * 128 + wn + l15;
  #pragma unroll
  for (int i = 0; i < 4; ++i)
    #pragma unroll
    for (int j = 0; j < 4; ++j) {
      float bv = bias[col0 + j * 16];
      #pragma unroll
      for (int r = 0; r < 4; ++r) {
        float v = acc[i][j][r] + bv;
        v = fmaxf(v, 0.f);
        out[(size_t)(row0 + i * 16 + r) * 1024 + (col0 + j * 16)] = v;
      }
    }
}

extern "C" void kernel_launch(void* const* d_in, const int* in_sizes, int n_in,
                              void* d_out, int out_size, void* d_ws, size_t ws_size,
                              hipStream_t stream) {
  (void)in_sizes; (void)n_in; (void)out_size; (void)ws_size;
  const float* x = (const float*)d_in[0];   // [8192,1024]
  const float* W = (const float*)d_in[1];   // [1024,8192]
  const float* b = (const float*)d_in[2];   // [1024]

  char* ws = (char*)d_ws;
  unsigned* scal = (unsigned*)ws;                       // [0]=amax_x bits, [1]=amax_h bits
  ushort* xq   = (ushort*)(ws + 256);                   // 16 MB
  ushort* xbf  = xq  + (size_t)8192 * 1024;             // 16 MB
  ushort* Wp   = xbf + (size_t)8192 * 1024;             // 16 MB [1024,8192]
  ushort* WpT  = Wp  + (size_t)1024 * 8192;             // 16 MB [8192,1024]
  ushort* Hcat = WpT + (size_t)8192 * 1024;             // 128 MB [8192,8192]

  hipMemsetAsync(scal, 0, 256, stream);  // ws is re-poisoned 0xAA before every call
  amax_x_kernel<<<2048, 256, 0, stream>>>((const float4*)x, 8192 * 1024 / 4, scal);
  prep_x_kernel<<<2048, 256, 0, stream>>>((const float4*)x, scal, xq, xbf, 8192 * 1024 / 4);
  prep_w_kernel<<<(1024 * 128 + 1024 * 1024 + 255) / 256, 256, 0, stream>>>(W, Wp);
  transpose_w_kernel<<<dim3(256, 32), dim3(32, 8), 0, stream>>>(Wp, WpT);
  gemm1_kernel<<<4096, 256, 0, stream>>>(xq, xbf, WpT, Hcat, scal + 1);
  quant_h_kernel<<<2048, 256, 0, stream>>>(Hcat, scal + 1);
  gemm2_kernel<<<512, 256, 0, stream>>>(Hcat, Wp, b, (float*)d_out);
}

// Round 4
// 453.585 us; speedup vs baseline: 1.3124x; 1.0341x over previous
//
#include <hip/hip_runtime.h>
#include <hip/hip_bf16.h>
#include <cstdint>

// Problem constants: W [N=1024, M=8192], x [B=8192, N=1024], b [1024]
// idx = 0..4095 (quantized cols), idx_comp = 4096..8191 (continuous cols)

using bf16x8 = __attribute__((ext_vector_type(8))) __bf16;
using f32x4  = __attribute__((ext_vector_type(4))) float;

typedef const __attribute__((address_space(1))) void g_void;
typedef __attribute__((address_space(3))) void l_void;

__device__ __forceinline__ void gload16(const void* g, void* l) {
  __builtin_amdgcn_global_load_lds((g_void*)g, (l_void*)l, 16, 0, 0);
}

__device__ __forceinline__ ushort f2bf(float f) {
  union { float f; unsigned u; } c; c.f = f;
  unsigned r = c.u + 0x7FFFu + ((c.u >> 16) & 1u);  // RNE truncate
  return (ushort)(r >> 16);
}
__device__ __forceinline__ float bf2f(ushort u) {
  union { unsigned u; float f; } c; c.u = ((unsigned)u) << 16;
  return c.f;
}

// ============ launch 1: W quant (blocks <16384) | W cast (<20480) | amax_x ============
__global__ void prep_wa_kernel(const float* __restrict__ W,
                               const float4* __restrict__ x,
                               ushort* __restrict__ Wp,
                               unsigned* __restrict__ amax_bits) {
  const int bidx = blockIdx.x;
  const int tid = threadIdx.x;

  if (bidx < 16384) {
    // ---- blockwise quant of W[:, :4096]: one 32-elem quant block per half-wave ----
    const int lane = tid & 63;
    const int wave = tid >> 6;
    const int e = lane & 31;            // element within quant block
    const int half = lane >> 5;         // which of the wave's 2 quant blocks
    const int qb = bidx * 8 + wave * 2 + half;   // 0..131071
    const int row = qb >> 7;
    const int m0 = (qb & 127) * 32;
    const float w = W[(size_t)row * 8192 + m0 + e];
    float aw = fabsf(w);
    // half-wave max reduce (xor masks <=16 stay within 32-lane half)
    float m = aw;
    #pragma unroll
    for (int d = 1; d <= 16; d <<= 1) m = fmaxf(m, __shfl_xor(m, d));
    // i1 = lowest index attaining max
    int idx = (aw == m) ? e : 32;
    #pragma unroll
    for (int d = 1; d <= 16; d <<= 1) idx = min(idx, __shfl_xor(idx, d));
    const int i1 = idx;
    // i2 = lowest index attaining max excluding i1
    float a2 = (e == i1) ? -1.f : aw;
    float m2 = a2;
    #pragma unroll
    for (int d = 1; d <= 16; d <<= 1) m2 = fmaxf(m2, __shfl_xor(m2, d));
    int idx2 = (a2 == m2) ? e : 32;
    #pragma unroll
    for (int d = 1; d <= 16; d <<= 1) idx2 = min(idx2, __shfl_xor(idx2, d));
    const int i2 = idx2;

    const float scale = fmaxf(m, 1e-8f);
    const float nb = w / scale;
    float q;
    if (e == i1 || e == i2) {
      q = rintf(nb * 7.f) / 7.f;
    } else {
      float s = (nb > 0.f) ? 1.f : ((nb < 0.f) ? -1.f : 0.f);
      q = s * ((fabsf(nb) > 0.66f) ? 1.f : (1.f / 3.f));
    }
    Wp[(size_t)row * 8192 + m0 + e] = f2bf(q * scale);
  } else if (bidx < 20480) {
    // ---- cast W[:, 4096:] to bf16 ----
    const int u = (bidx - 16384) * 256 + tid;   // 0 .. 1024*1024-1
    const int row = u >> 10;
    const int c4 = u & 1023;
    float4 v = *(const float4*)(W + (size_t)row * 8192 + 4096 + c4 * 4);
    ushort4 o;
    o.x = f2bf(v.x); o.y = f2bf(v.y); o.z = f2bf(v.z); o.w = f2bf(v.w);
    *(ushort4*)(Wp + (size_t)row * 8192 + 4096 + c4 * 4) = o;
  } else {
    // ---- amax(|x|) ----
    float m = 0.f;
    const int base = (bidx - 20480) * 256 + tid;
    const int stride = 2048 * 256;
    for (int i = base; i < 8192 * 1024 / 4; i += stride) {
      float4 v = x[i];
      m = fmaxf(m, fmaxf(fmaxf(fabsf(v.x), fabsf(v.y)),
                         fmaxf(fabsf(v.z), fabsf(v.w))));
    }
    #pragma unroll
    for (int off = 32; off > 0; off >>= 1) m = fmaxf(m, __shfl_down(m, off));
    __shared__ float wm[4];
    int lane = tid & 63, wave = tid >> 6;
    if (lane == 0) wm[wave] = m;
    __syncthreads();
    if (tid == 0) {
      float r = fmaxf(fmaxf(wm[0], wm[1]), fmaxf(wm[2], wm[3]));
      atomicMax(amax_bits, __float_as_uint(r));
    }
  }
}

// ============ launch 2: transpose Wp (blocks <2048) | prep_x ============
__global__ void prep_xt_kernel(const ushort* __restrict__ Wp,
                               ushort* __restrict__ WpT,
                               const float4* __restrict__ x,
                               const unsigned* __restrict__ amax_bits,
                               uint4* __restrict__ xq, uint4* __restrict__ xbf) {
  const int bidx = blockIdx.x;
  const int tid = threadIdx.x;

  if (bidx < 2048) {
    // ---- 64x64 bf16 transpose tile, ushort4 accesses ----
    __shared__ ushort tile[64][68];   // pad 68: conflict-free transposed reads
    const int ct = bidx & 127;        // col tile (8192/64)
    const int rt = bidx >> 7;         // row tile (1024/64)
    const int col0 = ct * 64, row0 = rt * 64;
    #pragma unroll
    for (int it = 0; it < 4; ++it) {
      const int r = (tid >> 4) + it * 16;
      const int c4 = (tid & 15) * 4;
      *(ushort4*)&tile[r][c4] =
          *(const ushort4*)(Wp + (size_t)(row0 + r) * 8192 + col0 + c4);
    }
    __syncthreads();
    #pragma unroll
    for (int it = 0; it < 4; ++it) {
      const int c = tid >> 2;
      const int rc = (tid & 3) + it * 4;
      ushort4 o;
      o.x = tile[rc * 4 + 0][c];
      o.y = tile[rc * 4 + 1][c];
      o.z = tile[rc * 4 + 2][c];
      o.w = tile[rc * 4 + 3][c];
      *(ushort4*)(WpT + (size_t)(col0 + c) * 1024 + row0 + rc * 4) = o;
    }
  } else {
    // ---- xq (fake-quant int8) + xbf (bf16 cast), 16B stores ----
    const float amax = fmaxf(__uint_as_float(*amax_bits), 1e-8f);
    const float scale = 127.f / amax;
    const int base = (bidx - 2048) * 256 + tid;
    const int stride = 2048 * 256;
    const int n8 = 8192 * 1024 / 8;
    for (int i = base; i < n8; i += stride) {
      float4 a = x[i * 2], b = x[i * 2 + 1];
      float v[8] = {a.x, a.y, a.z, a.w, b.x, b.y, b.z, b.w};
      unsigned qw[4], bw[4];
      #pragma unroll
      for (int j = 0; j < 4; ++j) {
        float q0 = fminf(fmaxf(rintf(v[2 * j] * scale), -128.f), 127.f) / scale;
        float q1 = fminf(fmaxf(rintf(v[2 * j + 1] * scale), -128.f), 127.f) / scale;
        qw[j] = (unsigned)f2bf(q0) | ((unsigned)f2bf(q1) << 16);
        bw[j] = (unsigned)f2bf(v[2 * j]) | ((unsigned)f2bf(v[2 * j + 1]) << 16);
      }
      xq[i] = make_uint4(qw[0], qw[1], qw[2], qw[3]);
      xbf[i] = make_uint4(bw[0], bw[1], bw[2], bw[3]);
    }
  }
}

// ---------------- GEMM1: Hcat[8192,8192] = [xq|xbf] @ Wprep, fused amax(|hidden_exp|) ----------------
// A: xq (bx<32) or xbf (bx>=32), [8192,1024]; B^T: WprepT [8192,1024].
// BK=64 as two BK=32 panels; one barrier-pair covers 32 MFMAs.
__global__ __launch_bounds__(256, 2) void gemm1_kernel(
    const ushort* __restrict__ Aq, const ushort* __restrict__ Af,
    const ushort* __restrict__ BT, ushort* __restrict__ C,
    unsigned* __restrict__ amax_bits) {
  __shared__ __align__(16) ushort As[2][128 * 32];
  __shared__ __align__(16) ushort Bs[2][128 * 32];
  __shared__ float wredmax[4];

  // XCD swizzle: l%8 = XCD; each XCD sweeps 8x8 block supertiles.
  const int l = blockIdx.x;
  const int xcd = l & 7;
  const int s = l >> 3;
  const int t = (xcd << 3) | (s >> 6);
  const int u = s & 63;
  const int bx = ((t & 7) << 3) | (u & 7);
  const int by = ((t >> 3) << 3) | (u >> 3);

  const int tid = threadIdx.x;
  const int lane = tid & 63, wave = tid >> 6;
  const int wm = (wave >> 1) << 6, wn = (wave & 1) << 6;
  const int l15 = lane & 15, quad = lane >> 4;

  const ushort* Abase = (bx < 32) ? Aq : Af;
  const ushort* Ag = Abase + (size_t)(by * 128 + (tid >> 2)) * 1024 + (tid & 3) * 8;
  const ushort* Bg = BT + (size_t)(bx * 128 + (tid >> 2)) * 1024 + (tid & 3) * 8;
  ushort* Asl0 = As[0] + tid * 8;
  ushort* Asl1 = As[1] + tid * 8;
  ushort* Bsl0 = Bs[0] + tid * 8;
  ushort* Bsl1 = Bs[1] + tid * 8;

  f32x4 acc[4][4];
  #pragma unroll
  for (int i = 0; i < 4; ++i)
    #pragma unroll
    for (int j = 0; j < 4; ++j) acc[i][j] = (f32x4){0.f, 0.f, 0.f, 0.f};

  for (int k0 = 0; k0 < 1024; k0 += 64) {
    __syncthreads();
    gload16(Ag + k0, Asl0);
    gload16(Ag + 64 * 1024 + k0, Asl0 + 64 * 32);
    gload16(Bg + k0, Bsl0);
    gload16(Bg + 64 * 1024 + k0, Bsl0 + 64 * 32);
    gload16(Ag + k0 + 32, Asl1);
    gload16(Ag + 64 * 1024 + k0 + 32, Asl1 + 64 * 32);
    gload16(Bg + k0 + 32, Bsl1);
    gload16(Bg + 64 * 1024 + k0 + 32, Bsl1 + 64 * 32);
    __syncthreads();

    #pragma unroll
    for (int p = 0; p < 2; ++p) {
      bf16x8 af[4], bfr[4];
      #pragma unroll
      for (int i = 0; i < 4; ++i)
        af[i] = *(const bf16x8*)&As[p][(wm + i * 16 + l15) * 32 + quad * 8];
      #pragma unroll
      for (int j = 0; j < 4; ++j)
        bfr[j] = *(const bf16x8*)&Bs[p][(wn + j * 16 + l15) * 32 + quad * 8];

      #pragma unroll
      for (int i = 0; i < 4; ++i)
        #pragma unroll
        for (int j = 0; j < 4; ++j)
          acc[i][j] = __builtin_amdgcn_mfma_f32_16x16x32_bf16(af[i], bfr[j], acc[i][j], 0, 0, 0);
    }
  }

  const int row0 = by * 128 + wm + quad * 4;
  const int col0 = bx * 128 + wn + l15;
  float lmax = 0.f;
  #pragma unroll
  for (int i = 0; i < 4; ++i)
    #pragma unroll
    for (int j = 0; j < 4; ++j)
      #pragma unroll
      for (int r = 0; r < 4; ++r) {
        float v = acc[i][j][r];
        lmax = fmaxf(lmax, fabsf(v));
        C[(size_t)(row0 + i * 16 + r) * 8192 + (col0 + j * 16)] = f2bf(v);
      }

  if (bx < 32) {  // amax only over hidden_exp half
    #pragma unroll
    for (int off = 32; off > 0; off >>= 1)
      lmax = fmaxf(lmax, __shfl_down(lmax, off));
    if (lane == 0) wredmax[wave] = lmax;
    __syncthreads();
    if (tid == 0) {
      float m = fmaxf(fmaxf(wredmax[0], wredmax[1]), fmaxf(wredmax[2], wredmax[3]));
      atomicMax(amax_bits, __float_as_uint(m));
    }
  }
}

// ---------------- quantize Hcat[:, :4096] in place (16B accesses) ----------------
__global__ void quant_h_kernel(ushort* __restrict__ H,
                               const unsigned* __restrict__ amax_bits) {
  const float amax = fmaxf(__uint_as_float(*amax_bits), 1e-8f);
  const float scale = 127.f / amax;
  const int n8 = 8192 * 4096 / 8;  // uint4 chunks
  for (int i = blockIdx.x * blockDim.x + threadIdx.x; i < n8;
       i += gridDim.x * blockDim.x) {
    const int row = i >> 9;       // 512 uint4-chunks per row-half
    const int c8 = i & 511;
    uint4* p = (uint4*)(H + (size_t)row * 8192) + c8;
    uint4 a = *p;
    unsigned w[4] = {a.x, a.y, a.z, a.w};
    #pragma unroll
    for (int j = 0; j < 4; ++j) {
      float lo = bf2f((ushort)(w[j] & 0xFFFF));
      float hi = bf2f((ushort)(w[j] >> 16));
      lo = fminf(fmaxf(rintf(lo * scale), -128.f), 127.f) / scale;
      hi = fminf(fmaxf(rintf(hi * scale), -128.f), 127.f) / scale;
      w[j] = (unsigned)f2bf(lo) | ((unsigned)f2bf(hi) << 16);
    }
    *p = make_uint4(w[0], w[1], w[2], w[3]);
  }
}

// ---------------- GEMM2: out[8192,1024] = relu(Hcat @ Wprep^T + b), fp32 out ----------------
// 512 blocks, all co-resident; XCD swizzle: each XCD owns 8 consecutive by
// row-tiles and sweeps all 8 bx, so each 2 MB A row-panel lives in one L2.
__global__ __launch_bounds__(256, 2) void gemm2_kernel(
    const ushort* __restrict__ A, const ushort* __restrict__ BT,
    const float* __restrict__ bias, float* __restrict__ out) {
  __shared__ __align__(16) ushort As[2][128 * 32];
  __shared__ __align__(16) ushort Bs[2][128 * 32];

  const int l = blockIdx.x;
  const int xcd = l & 7;
  const int s = l >> 3;
  const int by = (xcd << 3) | (s >> 3);
  const int bx = s & 7;

  const int tid = threadIdx.x;
  const int lane = tid & 63, wave = tid >> 6;
  const int wm = (wave >> 1) << 6, wn = (wave & 1) << 6;
  const int l15 = lane & 15, quad = lane >> 4;

  const ushort* Ag = A + (size_t)(by * 128 + (tid >> 2)) * 8192 + (tid & 3) * 8;
  const ushort* Bg = BT + (size_t)(bx * 128 + (tid >> 2)) * 8192 + (tid & 3) * 8;
  ushort* Asl0 = As[0] + tid * 8;
  ushort* Asl1 = As[1] + tid * 8;
  ushort* Bsl0 = Bs[0] + tid * 8;
  ushort* Bsl1 = Bs[1] + tid * 8;

  f32x4 acc[4][4];
  #pragma unroll
  for (int i = 0; i < 4; ++i)
    #pragma unroll
    for (int j = 0; j < 4; ++j) acc[i][j] = (f32x4){0.f, 0.f, 0.f, 0.f};

  for (int k0 = 0; k0 < 8192; k0 += 64) {
    __syncthreads();
    gload16(Ag + k0, Asl0);
    gload16(Ag + (size_t)64 * 8192 + k0, Asl0 + 64 * 32);
    gload16(Bg + k0, Bsl0);
    gload16(Bg + (size_t)64 * 8192 + k0, Bsl0 + 64 * 32);
    gload16(Ag + k0 + 32, Asl1);
    gload16(Ag + (size_t)64 * 8192 + k0 + 32, Asl1 + 64 * 32);
    gload16(Bg + k0 + 32, Bsl1);
    gload16(Bg + (size_t)64 * 8192 + k0 + 32, Bsl1 + 64 * 32);
    __syncthreads();

    #pragma unroll
    for (int p = 0; p < 2; ++p) {
      bf16x8 af[4], bfr[4];
      #pragma unroll
      for (int i = 0; i < 4; ++i)
        af[i] = *(const bf16x8*)&As[p][(wm + i * 16 + l15) * 32 + quad * 8];
      #pragma unroll
      for (int j = 0; j < 4; ++j)
        bfr[j] = *(const bf16x8*)&Bs[p][(wn + j * 16 + l15) * 32 + quad * 8];

      #pragma unroll
      for (int i = 0; i < 4; ++i)
        #pragma unroll
        for (int j = 0; j < 4; ++j)
          acc[i][j] = __builtin_amdgcn_mfma_f32_16x16x32_bf16(af[i], bfr[j], acc[i][j], 0, 0, 0);
    }
  }

  const int row0 = by * 128 + wm + quad * 4;
  const int col0 = bx * 128 + wn + l15;
  #pragma unroll
  for (int i = 0; i < 4; ++i)
    #pragma unroll
    for (int j = 0; j < 4; ++j) {
      float bv = bias[col0 + j * 16];
      #pragma unroll
      for (int r = 0; r < 4; ++r) {
        float v = acc[i][j][r] + bv;
        v = fmaxf(v, 0.f);
        out[(size_t)(row0 + i * 16 + r) * 1024 + (col0 + j * 16)] = v;
      }
    }
}

extern "C" void kernel_launch(void* const* d_in, const int* in_sizes, int n_in,
                              void* d_out, int out_size, void* d_ws, size_t ws_size,
                              hipStream_t stream) {
  (void)in_sizes; (void)n_in; (void)out_size; (void)ws_size;
  const float* x = (const float*)d_in[0];   // [8192,1024]
  const float* W = (const float*)d_in[1];   // [1024,8192]
  const float* b = (const float*)d_in[2];   // [1024]

  char* ws = (char*)d_ws;
  unsigned* scal = (unsigned*)ws;                       // [0]=amax_x bits, [1]=amax_h bits
  ushort* xq   = (ushort*)(ws + 256);                   // 16 MB
  ushort* xbf  = xq  + (size_t)8192 * 1024;             // 16 MB
  ushort* Wp   = xbf + (size_t)8192 * 1024;             // 16 MB [1024,8192]
  ushort* WpT  = Wp  + (size_t)1024 * 8192;             // 16 MB [8192,1024]
  ushort* Hcat = WpT + (size_t)8192 * 1024;             // 128 MB [8192,8192]

  hipMemsetAsync(scal, 0, 256, stream);  // ws is re-poisoned 0xAA before every call
  // launch 1: W-quant (16384 blocks) | W-cast (4096) | amax_x (2048)
  prep_wa_kernel<<<22528, 256, 0, stream>>>(W, (const float4*)x, Wp, scal);
  // launch 2: transpose (2048 blocks) | prep_x (2048)
  prep_xt_kernel<<<4096, 256, 0, stream>>>(Wp, WpT, (const float4*)x, scal,
                                           (uint4*)xq, (uint4*)xbf);
  gemm1_kernel<<<4096, 256, 0, stream>>>(xq, xbf, WpT, Hcat, scal + 1);
  quant_h_kernel<<<2048, 256, 0, stream>>>(Hcat, scal + 1);
  gemm2_kernel<<<512, 256, 0, stream>>>(Hcat, Wp, b, (float*)d_out);
}

// Round 6
// 369.338 us; speedup vs baseline: 1.6118x; 1.2281x over previous
//
#include <hip/hip_runtime.h>
#include <hip/hip_bf16.h>
#include <cstdint>

// Problem constants: W [N=1024, M=8192], x [B=8192, N=1024], b [1024]
// idx = 0..4095 (quantized cols), idx_comp = 4096..8191 (continuous cols)
//
// Algebraic restructure: hidden_cont = x@Wc is only consumed by
// hidden_cont@Wc^T, so the whole cont path = x @ (Wc@Wc^T) = x @ G with
// G [1024,1024] symmetric. Pipeline (all bf16 MFMA):
//   L1: W-quant -> Wq | Wc cast -> Wcb | amax_x
//   L2: G = Wcb@Wcb^T | transpose Wq -> WqT | prep_x (xq, xbf)
//   L3: gemm1: Hexp = xq @ Wq  [8192,4096] + amax_h
//   L4: quant_h in place
//   L5: gemm2: out = relu(Hq@Wq^T + xbf@G + b)   (split-K: 4096 + 1024)

using bf16x8 = __attribute__((ext_vector_type(8))) __bf16;
using f32x4  = __attribute__((ext_vector_type(4))) float;

typedef const __attribute__((address_space(1))) void g_void;
typedef __attribute__((address_space(3))) void l_void;

__device__ __forceinline__ void gload16(const void* g, void* l) {
  __builtin_amdgcn_global_load_lds((g_void*)g, (l_void*)l, 16, 0, 0);
}

__device__ __forceinline__ ushort f2bf(float f) {
  union { float f; unsigned u; } c; c.f = f;
  unsigned r = c.u + 0x7FFFu + ((c.u >> 16) & 1u);  // RNE truncate
  return (ushort)(r >> 16);
}
__device__ __forceinline__ float bf2f(ushort u) {
  union { unsigned u; float f; } c; c.u = ((unsigned)u) << 16;
  return c.f;
}

// ============ launch 1: W quant (blocks <16384) | Wc cast (<20480) | amax_x ============
__global__ void prep_wa_kernel(const float* __restrict__ W,
                               const float4* __restrict__ x,
                               ushort* __restrict__ Wq,
                               ushort* __restrict__ Wcb,
                               unsigned* __restrict__ amax_bits) {
  const int bidx = blockIdx.x;
  const int tid = threadIdx.x;

  if (bidx < 16384) {
    // ---- blockwise quant of W[:, :4096]: one 32-elem quant block per half-wave ----
    const int lane = tid & 63;
    const int wave = tid >> 6;
    const int e = lane & 31;
    const int half = lane >> 5;
    const int qb = bidx * 8 + wave * 2 + half;   // 0..131071
    const int row = qb >> 7;
    const int m0 = (qb & 127) * 32;
    const float w = W[(size_t)row * 8192 + m0 + e];
    float aw = fabsf(w);
    float m = aw;
    #pragma unroll
    for (int d = 1; d <= 16; d <<= 1) m = fmaxf(m, __shfl_xor(m, d));
    int idx = (aw == m) ? e : 32;
    #pragma unroll
    for (int d = 1; d <= 16; d <<= 1) idx = min(idx, __shfl_xor(idx, d));
    const int i1 = idx;
    float a2 = (e == i1) ? -1.f : aw;
    float m2 = a2;
    #pragma unroll
    for (int d = 1; d <= 16; d <<= 1) m2 = fmaxf(m2, __shfl_xor(m2, d));
    int idx2 = (a2 == m2) ? e : 32;
    #pragma unroll
    for (int d = 1; d <= 16; d <<= 1) idx2 = min(idx2, __shfl_xor(idx2, d));
    const int i2 = idx2;

    const float scale = fmaxf(m, 1e-8f);
    const float nb = w / scale;
    float q;
    if (e == i1 || e == i2) {
      q = rintf(nb * 7.f) / 7.f;
    } else {
      float s = (nb > 0.f) ? 1.f : ((nb < 0.f) ? -1.f : 0.f);
      q = s * ((fabsf(nb) > 0.66f) ? 1.f : (1.f / 3.f));
    }
    Wq[(size_t)row * 4096 + m0 + e] = f2bf(q * scale);
  } else if (bidx < 20480) {
    // ---- cast W[:, 4096:] to bf16 -> Wcb [1024,4096] ----
    const int u = (bidx - 16384) * 256 + tid;   // 0 .. 1024*1024-1
    const int row = u >> 10;
    const int c4 = u & 1023;
    float4 v = *(const float4*)(W + (size_t)row * 8192 + 4096 + c4 * 4);
    ushort4 o;
    o.x = f2bf(v.x); o.y = f2bf(v.y); o.z = f2bf(v.z); o.w = f2bf(v.w);
    *(ushort4*)(Wcb + (size_t)row * 4096 + c4 * 4) = o;
  } else {
    // ---- amax(|x|) ----
    float m = 0.f;
    const int base = (bidx - 20480) * 256 + tid;
    const int stride = 2048 * 256;
    for (int i = base; i < 8192 * 1024 / 4; i += stride) {
      float4 v = x[i];
      m = fmaxf(m, fmaxf(fmaxf(fabsf(v.x), fabsf(v.y)),
                         fmaxf(fabsf(v.z), fabsf(v.w))));
    }
    #pragma unroll
    for (int off = 32; off > 0; off >>= 1) m = fmaxf(m, __shfl_down(m, off));
    __shared__ float wm[4];
    int lane = tid & 63, wave = tid >> 6;
    if (lane == 0) wm[wave] = m;
    __syncthreads();
    if (tid == 0) {
      float r = fmaxf(fmaxf(wm[0], wm[1]), fmaxf(wm[2], wm[3]));
      atomicMax(amax_bits, __float_as_uint(r));
    }
  }
}

// ============ launch 2: G-GEMM (blocks <256) | transpose Wq (<1280) | prep_x ============
__global__ void prep_g_kernel(const ushort* __restrict__ Wcb,
                              ushort* __restrict__ G,
                              const ushort* __restrict__ Wq,
                              ushort* __restrict__ WqT,
                              const float4* __restrict__ x,
                              const unsigned* __restrict__ amax_bits,
                              uint4* __restrict__ xq, uint4* __restrict__ xbf) {
  const int bidx = blockIdx.x;
  const int tid = threadIdx.x;

  if (bidx < 256) {
    // ---- G[i,j] = sum_m Wcb[i,m]*Wcb[j,m]; 64x64 tile per block ----
    __shared__ __align__(16) ushort As[2][64 * 32];
    __shared__ __align__(16) ushort Bs[2][64 * 32];
    const int gy = bidx >> 4, gx = bidx & 15;   // 16x16 tiles of 64
    const int i0 = gy * 64, j0 = gx * 64;

    const int lane = tid & 63, wave = tid >> 6;
    const int wm2 = (wave >> 1) << 5, wn2 = (wave & 1) << 5;
    const int l15 = lane & 15, quad = lane >> 4;

    const ushort* Ag = Wcb + (size_t)(i0 + (tid >> 2)) * 4096 + (tid & 3) * 8;
    const ushort* Bg = Wcb + (size_t)(j0 + (tid >> 2)) * 4096 + (tid & 3) * 8;
    ushort* Asl0 = As[0] + tid * 8; ushort* Asl1 = As[1] + tid * 8;
    ushort* Bsl0 = Bs[0] + tid * 8; ushort* Bsl1 = Bs[1] + tid * 8;

    f32x4 acc[2][2];
    #pragma unroll
    for (int i = 0; i < 2; ++i)
      #pragma unroll
      for (int j = 0; j < 2; ++j) acc[i][j] = (f32x4){0.f, 0.f, 0.f, 0.f};

    for (int k0 = 0; k0 < 4096; k0 += 64) {
      __syncthreads();
      gload16(Ag + k0, Asl0);
      gload16(Bg + k0, Bsl0);
      gload16(Ag + k0 + 32, Asl1);
      gload16(Bg + k0 + 32, Bsl1);
      __syncthreads();
      #pragma unroll
      for (int p = 0; p < 2; ++p) {
        bf16x8 af[2], bfr[2];
        #pragma unroll
        for (int i = 0; i < 2; ++i)
          af[i] = *(const bf16x8*)&As[p][(wm2 + i * 16 + l15) * 32 + quad * 8];
        #pragma unroll
        for (int j = 0; j < 2; ++j)
          bfr[j] = *(const bf16x8*)&Bs[p][(wn2 + j * 16 + l15) * 32 + quad * 8];
        #pragma unroll
        for (int i = 0; i < 2; ++i)
          #pragma unroll
          for (int j = 0; j < 2; ++j)
            acc[i][j] = __builtin_amdgcn_mfma_f32_16x16x32_bf16(af[i], bfr[j], acc[i][j], 0, 0, 0);
      }
    }
    const int row0 = i0 + wm2 + quad * 4;
    const int col0 = j0 + wn2 + l15;
    #pragma unroll
    for (int i = 0; i < 2; ++i)
      #pragma unroll
      for (int j = 0; j < 2; ++j)
        #pragma unroll
        for (int r = 0; r < 4; ++r)
          G[(size_t)(row0 + i * 16 + r) * 1024 + (col0 + j * 16)] = f2bf(acc[i][j][r]);
  } else if (bidx < 1280) {
    // ---- 64x64 bf16 transpose: Wq [1024,4096] -> WqT [4096,1024] ----
    __shared__ ushort tile[64][68];
    const int v = bidx - 256;
    const int ct = v & 63;            // col tile (4096/64)
    const int rt = v >> 6;            // row tile (1024/64)
    const int col0 = ct * 64, row0 = rt * 64;
    #pragma unroll
    for (int it = 0; it < 4; ++it) {
      const int r = (tid >> 4) + it * 16;
      const int c4 = (tid & 15) * 4;
      *(ushort4*)&tile[r][c4] =
          *(const ushort4*)(Wq + (size_t)(row0 + r) * 4096 + col0 + c4);
    }
    __syncthreads();
    #pragma unroll
    for (int it = 0; it < 4; ++it) {
      const int c = tid >> 2;
      const int rc = (tid & 3) + it * 4;
      ushort4 o;
      o.x = tile[rc * 4 + 0][c];
      o.y = tile[rc * 4 + 1][c];
      o.z = tile[rc * 4 + 2][c];
      o.w = tile[rc * 4 + 3][c];
      *(ushort4*)(WqT + (size_t)(col0 + c) * 1024 + row0 + rc * 4) = o;
    }
  } else {
    // ---- xq (fake-quant int8) + xbf (bf16 cast), 16B stores ----
    const float amax = fmaxf(__uint_as_float(*amax_bits), 1e-8f);
    const float scale = 127.f / amax;
    const int base = (bidx - 1280) * 256 + tid;
    const int stride = 2048 * 256;
    const int n8 = 8192 * 1024 / 8;
    for (int i = base; i < n8; i += stride) {
      float4 a = x[i * 2], b = x[i * 2 + 1];
      float v[8] = {a.x, a.y, a.z, a.w, b.x, b.y, b.z, b.w};
      unsigned qw[4], bw[4];
      #pragma unroll
      for (int j = 0; j < 4; ++j) {
        float q0 = fminf(fmaxf(rintf(v[2 * j] * scale), -128.f), 127.f) / scale;
        float q1 = fminf(fmaxf(rintf(v[2 * j + 1] * scale), -128.f), 127.f) / scale;
        qw[j] = (unsigned)f2bf(q0) | ((unsigned)f2bf(q1) << 16);
        bw[j] = (unsigned)f2bf(v[2 * j]) | ((unsigned)f2bf(v[2 * j + 1]) << 16);
      }
      xq[i] = make_uint4(qw[0], qw[1], qw[2], qw[3]);
      xbf[i] = make_uint4(bw[0], bw[1], bw[2], bw[3]);
    }
  }
}

// ---------------- GEMM1: Hexp[8192,4096] = xq @ Wq, fused amax ----------------
// A: xq [8192,1024]; B^T: WqT [4096,1024]. BK=64 as two BK=32 panels.
__global__ __launch_bounds__(256, 2) void gemm1_kernel(
    const ushort* __restrict__ Aq, const ushort* __restrict__ BT,
    ushort* __restrict__ Hexp, unsigned* __restrict__ amax_bits) {
  __shared__ __align__(16) ushort As[2][128 * 32];
  __shared__ __align__(16) ushort Bs[2][128 * 32];
  __shared__ float wredmax[4];

  // 2048 blocks; XCD swizzle: xcd = l%8 owns 4 supertiles of 8x8 blocks.
  const int l = blockIdx.x;
  const int xcd = l & 7;
  const int s = l >> 3;                     // 0..255
  const int t = (xcd << 2) | (s >> 6);      // 0..31
  const int u = s & 63;
  const int bx = ((t & 3) << 3) | (u & 7);  // 0..31
  const int by = ((t >> 2) << 3) | (u >> 3);// 0..63

  const int tid = threadIdx.x;
  const int lane = tid & 63, wave = tid >> 6;
  const int wm = (wave >> 1) << 6, wn = (wave & 1) << 6;
  const int l15 = lane & 15, quad = lane >> 4;

  const ushort* Ag = Aq + (size_t)(by * 128 + (tid >> 2)) * 1024 + (tid & 3) * 8;
  const ushort* Bg = BT + (size_t)(bx * 128 + (tid >> 2)) * 1024 + (tid & 3) * 8;
  ushort* Asl0 = As[0] + tid * 8; ushort* Asl1 = As[1] + tid * 8;
  ushort* Bsl0 = Bs[0] + tid * 8; ushort* Bsl1 = Bs[1] + tid * 8;

  f32x4 acc[4][4];
  #pragma unroll
  for (int i = 0; i < 4; ++i)
    #pragma unroll
    for (int j = 0; j < 4; ++j) acc[i][j] = (f32x4){0.f, 0.f, 0.f, 0.f};

  for (int k0 = 0; k0 < 1024; k0 += 64) {
    __syncthreads();
    gload16(Ag + k0, Asl0);
    gload16(Ag + 64 * 1024 + k0, Asl0 + 64 * 32);
    gload16(Bg + k0, Bsl0);
    gload16(Bg + 64 * 1024 + k0, Bsl0 + 64 * 32);
    gload16(Ag + k0 + 32, Asl1);
    gload16(Ag + 64 * 1024 + k0 + 32, Asl1 + 64 * 32);
    gload16(Bg + k0 + 32, Bsl1);
    gload16(Bg + 64 * 1024 + k0 + 32, Bsl1 + 64 * 32);
    __syncthreads();

    #pragma unroll
    for (int p = 0; p < 2; ++p) {
      bf16x8 af[4], bfr[4];
      #pragma unroll
      for (int i = 0; i < 4; ++i)
        af[i] = *(const bf16x8*)&As[p][(wm + i * 16 + l15) * 32 + quad * 8];
      #pragma unroll
      for (int j = 0; j < 4; ++j)
        bfr[j] = *(const bf16x8*)&Bs[p][(wn + j * 16 + l15) * 32 + quad * 8];
      #pragma unroll
      for (int i = 0; i < 4; ++i)
        #pragma unroll
        for (int j = 0; j < 4; ++j)
          acc[i][j] = __builtin_amdgcn_mfma_f32_16x16x32_bf16(af[i], bfr[j], acc[i][j], 0, 0, 0);
    }
  }

  const int row0 = by * 128 + wm + quad * 4;
  const int col0 = bx * 128 + wn + l15;
  float lmax = 0.f;
  #pragma unroll
  for (int i = 0; i < 4; ++i)
    #pragma unroll
    for (int j = 0; j < 4; ++j)
      #pragma unroll
      for (int r = 0; r < 4; ++r) {
        float v = acc[i][j][r];
        lmax = fmaxf(lmax, fabsf(v));
        Hexp[(size_t)(row0 + i * 16 + r) * 4096 + (col0 + j * 16)] = f2bf(v);
      }

  #pragma unroll
  for (int off = 32; off > 0; off >>= 1)
    lmax = fmaxf(lmax, __shfl_down(lmax, off));
  if (lane == 0) wredmax[wave] = lmax;
  __syncthreads();
  if (tid == 0) {
    float m = fmaxf(fmaxf(wredmax[0], wredmax[1]), fmaxf(wredmax[2], wredmax[3]));
    atomicMax(amax_bits, __float_as_uint(m));
  }
}

// ---------------- quantize Hexp [8192,4096] in place (16B accesses) ----------------
__global__ void quant_h_kernel(ushort* __restrict__ H,
                               const unsigned* __restrict__ amax_bits) {
  const float amax = fmaxf(__uint_as_float(*amax_bits), 1e-8f);
  const float scale = 127.f / amax;
  const int n8 = 8192 * 4096 / 8;  // uint4 chunks (contiguous array)
  for (int i = blockIdx.x * blockDim.x + threadIdx.x; i < n8;
       i += gridDim.x * blockDim.x) {
    uint4* p = (uint4*)H + i;
    uint4 a = *p;
    unsigned w[4] = {a.x, a.y, a.z, a.w};
    #pragma unroll
    for (int j = 0; j < 4; ++j) {
      float lo = bf2f((ushort)(w[j] & 0xFFFF));
      float hi = bf2f((ushort)(w[j] >> 16));
      lo = fminf(fmaxf(rintf(lo * scale), -128.f), 127.f) / scale;
      hi = fminf(fmaxf(rintf(hi * scale), -128.f), 127.f) / scale;
      w[j] = (unsigned)f2bf(lo) | ((unsigned)f2bf(hi) << 16);
    }
    *p = make_uint4(w[0], w[1], w[2], w[3]);
  }
}

// ---------------- GEMM2: out[8192,1024] = relu(Hq@Wq^T + xbf@G + b) ----------------
// Split-K: loop1 K=4096 over (Hq [8192,4096], Wq [1024,4096] B^T-layout),
// loop2 K=1024 over (xbf [8192,1024], G [1024,1024] symmetric = B^T-layout).
// 512 blocks; XCD swizzle: each XCD owns 8 consecutive by row-tiles.
__global__ __launch_bounds__(256, 2) void gemm2_kernel(
    const ushort* __restrict__ Hq, const ushort* __restrict__ Wq,
    const ushort* __restrict__ Xb, const ushort* __restrict__ G,
    const float* __restrict__ bias, float* __restrict__ out) {
  __shared__ __align__(16) ushort As[2][128 * 32];
  __shared__ __align__(16) ushort Bs[2][128 * 32];

  const int l = blockIdx.x;
  const int xcd = l & 7;
  const int s = l >> 3;
  const int by = (xcd << 3) | (s >> 3);
  const int bx = s & 7;

  const int tid = threadIdx.x;
  const int lane = tid & 63, wave = tid >> 6;
  const int wm = (wave >> 1) << 6, wn = (wave & 1) << 6;
  const int l15 = lane & 15, quad = lane >> 4;

  ushort* Asl0 = As[0] + tid * 8; ushort* Asl1 = As[1] + tid * 8;
  ushort* Bsl0 = Bs[0] + tid * 8; ushort* Bsl1 = Bs[1] + tid * 8;

  f32x4 acc[4][4];
  #pragma unroll
  for (int i = 0; i < 4; ++i)
    #pragma unroll
    for (int j = 0; j < 4; ++j) acc[i][j] = (f32x4){0.f, 0.f, 0.f, 0.f};

  // ---- loop 1: K=4096 over Hq / Wq (stride 4096) ----
  {
    const ushort* Ag = Hq + (size_t)(by * 128 + (tid >> 2)) * 4096 + (tid & 3) * 8;
    const ushort* Bg = Wq + (size_t)(bx * 128 + (tid >> 2)) * 4096 + (tid & 3) * 8;
    for (int k0 = 0; k0 < 4096; k0 += 64) {
      __syncthreads();
      gload16(Ag + k0, Asl0);
      gload16(Ag + (size_t)64 * 4096 + k0, Asl0 + 64 * 32);
      gload16(Bg + k0, Bsl0);
      gload16(Bg + (size_t)64 * 4096 + k0, Bsl0 + 64 * 32);
      gload16(Ag + k0 + 32, Asl1);
      gload16(Ag + (size_t)64 * 4096 + k0 + 32, Asl1 + 64 * 32);
      gload16(Bg + k0 + 32, Bsl1);
      gload16(Bg + (size_t)64 * 4096 + k0 + 32, Bsl1 + 64 * 32);
      __syncthreads();
      #pragma unroll
      for (int p = 0; p < 2; ++p) {
        bf16x8 af[4], bfr[4];
        #pragma unroll
        for (int i = 0; i < 4; ++i)
          af[i] = *(const bf16x8*)&As[p][(wm + i * 16 + l15) * 32 + quad * 8];
        #pragma unroll
        for (int j = 0; j < 4; ++j)
          bfr[j] = *(const bf16x8*)&Bs[p][(wn + j * 16 + l15) * 32 + quad * 8];
        #pragma unroll
        for (int i = 0; i < 4; ++i)
          #pragma unroll
          for (int j = 0; j < 4; ++j)
            acc[i][j] = __builtin_amdgcn_mfma_f32_16x16x32_bf16(af[i], bfr[j], acc[i][j], 0, 0, 0);
      }
    }
  }
  // ---- loop 2: K=1024 over xbf / G (stride 1024) ----
  {
    const ushort* Ag = Xb + (size_t)(by * 128 + (tid >> 2)) * 1024 + (tid & 3) * 8;
    const ushort* Bg = G + (size_t)(bx * 128 + (tid >> 2)) * 1024 + (tid & 3) * 8;
    for (int k0 = 0; k0 < 1024; k0 += 64) {
      __syncthreads();
      gload16(Ag + k0, Asl0);
      gload16(Ag + 64 * 1024 + k0, Asl0 + 64 * 32);
      gload16(Bg + k0, Bsl0);
      gload16(Bg + 64 * 1024 + k0, Bsl0 + 64 * 32);
      gload16(Ag + k0 + 32, Asl1);
      gload16(Ag + 64 * 1024 + k0 + 32, Asl1 + 64 * 32);
      gload16(Bg + k0 + 32, Bsl1);
      gload16(Bg + 64 * 1024 + k0 + 32, Bsl1 + 64 * 32);
      __syncthreads();
      #pragma unroll
      for (int p = 0; p < 2; ++p) {
        bf16x8 af[4], bfr[4];
        #pragma unroll
        for (int i = 0; i < 4; ++i)
          af[i] = *(const bf16x8*)&As[p][(wm + i * 16 + l15) * 32 + quad * 8];
        #pragma unroll
        for (int j = 0; j < 4; ++j)
          bfr[j] = *(const bf16x8*)&Bs[p][(wn + j * 16 + l15) * 32 + quad * 8];
        #pragma unroll
        for (int i = 0; i < 4; ++i)
          #pragma unroll
          for (int j = 0; j < 4; ++j)
            acc[i][j] = __builtin_amdgcn_mfma_f32_16x16x32_bf16(af[i], bfr[j], acc[i][j], 0, 0, 0);
      }
    }
  }

  const int row0 = by * 128 + wm + quad * 4;
  const int col0 = bx * 128 + wn + l15;
  #pragma unroll
  for (int i = 0; i < 4; ++i)
    #pragma unroll
    for (int j = 0; j < 4; ++j) {
      float bv = bias[col0 + j * 16];
      #pragma unroll
      for (int r = 0; r < 4; ++r) {
        float v = acc[i][j][r] + bv;
        v = fmaxf(v, 0.f);
        out[(size_t)(row0 + i * 16 + r) * 1024 + (col0 + j * 16)] = v;
      }
    }
}

extern "C" void kernel_launch(void* const* d_in, const int* in_sizes, int n_in,
                              void* d_out, int out_size, void* d_ws, size_t ws_size,
                              hipStream_t stream) {
  (void)in_sizes; (void)n_in; (void)out_size; (void)ws_size;
  const float* x = (const float*)d_in[0];   // [8192,1024]
  const float* W = (const float*)d_in[1];   // [1024,8192]
  const float* b = (const float*)d_in[2];   // [1024]

  char* ws = (char*)d_ws;
  unsigned* scal = (unsigned*)ws;                      // [0]=amax_x, [1]=amax_h
  ushort* xq   = (ushort*)(ws + 256);                  // 16 MB [8192,1024]
  ushort* xbf  = xq   + (size_t)8192 * 1024;           // 16 MB [8192,1024]
  ushort* Wq   = xbf  + (size_t)8192 * 1024;           //  8 MB [1024,4096]
  ushort* WqT  = Wq   + (size_t)1024 * 4096;           //  8 MB [4096,1024]
  ushort* Wcb  = WqT  + (size_t)4096 * 1024;           //  8 MB [1024,4096]
  ushort* G    = Wcb  + (size_t)1024 * 4096;           //  2 MB [1024,1024]
  ushort* Hexp = G    + (size_t)1024 * 1024;           // 64 MB [8192,4096]

  hipMemsetAsync(scal, 0, 256, stream);  // ws is re-poisoned 0xAA before every call
  // L1: W-quant (16384 blocks) | Wc-cast (4096) | amax_x (2048)
  prep_wa_kernel<<<22528, 256, 0, stream>>>(W, (const float4*)x, Wq, Wcb, scal);
  // L2: G-GEMM (256) | transpose (1024) | prep_x (2048)
  prep_g_kernel<<<3328, 256, 0, stream>>>(Wcb, G, Wq, WqT, (const float4*)x, scal,
                                          (uint4*)xq, (uint4*)xbf);
  gemm1_kernel<<<2048, 256, 0, stream>>>(xq, WqT, Hexp, scal + 1);
  quant_h_kernel<<<2048, 256, 0, stream>>>(Hexp, scal + 1);
  gemm2_kernel<<<512, 256, 0, stream>>>(Hexp, Wq, xbf, G, b, (float*)d_out);
}

// Round 10
// 358.323 us; speedup vs baseline: 1.6613x; 1.0307x over previous
//
#include <hip/hip_runtime.h>
#include <hip/hip_bf16.h>
#include <cstdint>

// Problem constants: W [N=1024, M=8192], x [B=8192, N=1024], b [1024]
// idx = 0..4095 (quantized cols), idx_comp = 4096..8191 (continuous cols)
//
// Algebraic restructure: cont path = x @ (Wc@Wc^T) = x @ G, G [1024,1024] sym.
// Launch DAG (all bf16 MFMA; every code path HW-validated in round 6's bench,
// only the launch packing of the G-GEMM differs):
//   L1: W-quant -> Wq | Wc cast -> Wcb | amax_x
//   L2: transpose Wq -> WqT | prep_x (xq, xbf)
//   L3: G = Wcb@Wcb^T (blocks<256, hidden under gemm1) | gemm1: Hexp = xq@Wq + amax_h
//   L4: quant_h in place
//   L5: gemm2: out = relu(Hq@Wq^T + xbf@G + b)   (split-K: 4096 + 1024)

using bf16x8 = __attribute__((ext_vector_type(8))) __bf16;
using f32x4  = __attribute__((ext_vector_type(4))) float;

typedef const __attribute__((address_space(1))) void g_void;
typedef __attribute__((address_space(3))) void l_void;

__device__ __forceinline__ void gload16(const void* g, void* l) {
  __builtin_amdgcn_global_load_lds((g_void*)g, (l_void*)l, 16, 0, 0);
}

__device__ __forceinline__ ushort f2bf(float f) {
  union { float f; unsigned u; } c; c.f = f;
  unsigned r = c.u + 0x7FFFu + ((c.u >> 16) & 1u);  // RNE truncate
  return (ushort)(r >> 16);
}
__device__ __forceinline__ float bf2f(ushort u) {
  union { unsigned u; float f; } c; c.u = ((unsigned)u) << 16;
  return c.f;
}

// ============ L1: W quant (blocks <16384) | Wc cast (<20480) | amax_x ============
__global__ void prep_wa_kernel(const float* __restrict__ W,
                               const float4* __restrict__ x,
                               ushort* __restrict__ Wq,
                               ushort* __restrict__ Wcb,
                               unsigned* __restrict__ amax_bits) {
  const int bidx = blockIdx.x;
  const int tid = threadIdx.x;

  if (bidx < 16384) {
    // ---- blockwise quant of W[:, :4096]: one 32-elem quant block per half-wave ----
    const int lane = tid & 63;
    const int wave = tid >> 6;
    const int e = lane & 31;
    const int half = lane >> 5;
    const int qb = bidx * 8 + wave * 2 + half;   // 0..131071
    const int row = qb >> 7;
    const int m0 = (qb & 127) * 32;
    const float w = W[(size_t)row * 8192 + m0 + e];
    float aw = fabsf(w);
    float m = aw;
    #pragma unroll
    for (int d = 1; d <= 16; d <<= 1) m = fmaxf(m, __shfl_xor(m, d));
    int idx = (aw == m) ? e : 32;
    #pragma unroll
    for (int d = 1; d <= 16; d <<= 1) idx = min(idx, __shfl_xor(idx, d));
    const int i1 = idx;
    float a2 = (e == i1) ? -1.f : aw;
    float m2 = a2;
    #pragma unroll
    for (int d = 1; d <= 16; d <<= 1) m2 = fmaxf(m2, __shfl_xor(m2, d));
    int idx2 = (a2 == m2) ? e : 32;
    #pragma unroll
    for (int d = 1; d <= 16; d <<= 1) idx2 = min(idx2, __shfl_xor(idx2, d));
    const int i2 = idx2;

    const float scale = fmaxf(m, 1e-8f);
    const float nb = w / scale;
    float q;
    if (e == i1 || e == i2) {
      q = rintf(nb * 7.f) / 7.f;
    } else {
      float s = (nb > 0.f) ? 1.f : ((nb < 0.f) ? -1.f : 0.f);
      q = s * ((fabsf(nb) > 0.66f) ? 1.f : (1.f / 3.f));
    }
    Wq[(size_t)row * 4096 + m0 + e] = f2bf(q * scale);
  } else if (bidx < 20480) {
    // ---- cast W[:, 4096:] to bf16 -> Wcb [1024,4096] ----
    const int u = (bidx - 16384) * 256 + tid;   // 0 .. 1024*1024-1
    const int row = u >> 10;
    const int c4 = u & 1023;
    float4 v = *(const float4*)(W + (size_t)row * 8192 + 4096 + c4 * 4);
    ushort4 o;
    o.x = f2bf(v.x); o.y = f2bf(v.y); o.z = f2bf(v.z); o.w = f2bf(v.w);
    *(ushort4*)(Wcb + (size_t)row * 4096 + c4 * 4) = o;
  } else {
    // ---- amax(|x|) ----
    float m = 0.f;
    const int base = (bidx - 20480) * 256 + tid;
    const int stride = 2048 * 256;
    for (int i = base; i < 8192 * 1024 / 4; i += stride) {
      float4 v = x[i];
      m = fmaxf(m, fmaxf(fmaxf(fabsf(v.x), fabsf(v.y)),
                         fmaxf(fabsf(v.z), fabsf(v.w))));
    }
    #pragma unroll
    for (int off = 32; off > 0; off >>= 1) m = fmaxf(m, __shfl_down(m, off));
    __shared__ float wm[4];
    int lane = tid & 63, wave = tid >> 6;
    if (lane == 0) wm[wave] = m;
    __syncthreads();
    if (tid == 0) {
      float r = fmaxf(fmaxf(wm[0], wm[1]), fmaxf(wm[2], wm[3]));
      atomicMax(amax_bits, __float_as_uint(r));
    }
  }
}

// ============ L2: transpose Wq (blocks <1024) | prep_x ============
__global__ void prep_xt_kernel(const ushort* __restrict__ Wq,
                               ushort* __restrict__ WqT,
                               const float4* __restrict__ x,
                               const unsigned* __restrict__ amax_bits,
                               uint4* __restrict__ xq, uint4* __restrict__ xbf) {
  const int bidx = blockIdx.x;
  const int tid = threadIdx.x;

  if (bidx < 1024) {
    // ---- 64x64 bf16 transpose: Wq [1024,4096] -> WqT [4096,1024] ----
    __shared__ ushort tile[64][68];
    const int ct = bidx & 63;         // col tile (4096/64)
    const int rt = bidx >> 6;         // row tile (1024/64)
    const int col0 = ct * 64, row0 = rt * 64;
    #pragma unroll
    for (int it = 0; it < 4; ++it) {
      const int r = (tid >> 4) + it * 16;
      const int c4 = (tid & 15) * 4;
      *(ushort4*)&tile[r][c4] =
          *(const ushort4*)(Wq + (size_t)(row0 + r) * 4096 + col0 + c4);
    }
    __syncthreads();
    #pragma unroll
    for (int it = 0; it < 4; ++it) {
      const int c = tid >> 2;
      const int rc = (tid & 3) + it * 4;
      ushort4 o;
      o.x = tile[rc * 4 + 0][c];
      o.y = tile[rc * 4 + 1][c];
      o.z = tile[rc * 4 + 2][c];
      o.w = tile[rc * 4 + 3][c];
      *(ushort4*)(WqT + (size_t)(col0 + c) * 1024 + row0 + rc * 4) = o;
    }
  } else {
    // ---- xq (fake-quant int8) + xbf (bf16 cast), 16B stores ----
    const float amax = fmaxf(__uint_as_float(*amax_bits), 1e-8f);
    const float scale = 127.f / amax;
    const int base = (bidx - 1024) * 256 + tid;
    const int stride = 2048 * 256;
    const int n8 = 8192 * 1024 / 8;
    for (int i = base; i < n8; i += stride) {
      float4 a = x[i * 2], b = x[i * 2 + 1];
      float v[8] = {a.x, a.y, a.z, a.w, b.x, b.y, b.z, b.w};
      unsigned qw[4], bw[4];
      #pragma unroll
      for (int j = 0; j < 4; ++j) {
        float q0 = fminf(fmaxf(rintf(v[2 * j] * scale), -128.f), 127.f) / scale;
        float q1 = fminf(fmaxf(rintf(v[2 * j + 1] * scale), -128.f), 127.f) / scale;
        qw[j] = (unsigned)f2bf(q0) | ((unsigned)f2bf(q1) << 16);
        bw[j] = (unsigned)f2bf(v[2 * j]) | ((unsigned)f2bf(v[2 * j + 1]) << 16);
      }
      xq[i] = make_uint4(qw[0], qw[1], qw[2], qw[3]);
      xbf[i] = make_uint4(bw[0], bw[1], bw[2], bw[3]);
    }
  }
}

// ============ L3: G-GEMM (blocks <256, reads Wcb bf16) | gemm1 ============
// G branch is the round-6-benched prep_g G-GEMM, LDS re-pointed at As/Bs.
__global__ __launch_bounds__(256, 2) void gemm1_kernel(
    const ushort* __restrict__ Wcb,
    ushort* __restrict__ G,
    const ushort* __restrict__ Aq, const ushort* __restrict__ BT,
    ushort* __restrict__ Hexp, unsigned* __restrict__ amax_bits) {
  __shared__ __align__(16) ushort As[2][128 * 32];
  __shared__ __align__(16) ushort Bs[2][128 * 32];
  __shared__ float wredmax[4];

  const int bidx = blockIdx.x;
  const int tid = threadIdx.x;
  const int lane = tid & 63, wave = tid >> 6;
  const int l15 = lane & 15, quad = lane >> 4;

  if (bidx < 256) {
    // ---- G[i,j] = sum_m Wcb[i,m]*Wcb[j,m]; 64x64 tile per block ----
    const int gy = bidx >> 4, gx = bidx & 15;
    const int i0 = gy * 64, j0 = gx * 64;
    const int wm2 = (wave >> 1) << 5, wn2 = (wave & 1) << 5;

    const ushort* Ag = Wcb + (size_t)(i0 + (tid >> 2)) * 4096 + (tid & 3) * 8;
    const ushort* Bg = Wcb + (size_t)(j0 + (tid >> 2)) * 4096 + (tid & 3) * 8;
    ushort* Asl = (ushort*)As;   // panels of 64*32 = 2048 ushorts per p
    ushort* Bsl = (ushort*)Bs;

    f32x4 acc[2][2];
    #pragma unroll
    for (int i = 0; i < 2; ++i)
      #pragma unroll
      for (int j = 0; j < 2; ++j) acc[i][j] = (f32x4){0.f, 0.f, 0.f, 0.f};

    for (int k0 = 0; k0 < 4096; k0 += 64) {
      __syncthreads();
      gload16(Ag + k0, Asl + tid * 8);
      gload16(Bg + k0, Bsl + tid * 8);
      gload16(Ag + k0 + 32, Asl + 2048 + tid * 8);
      gload16(Bg + k0 + 32, Bsl + 2048 + tid * 8);
      __syncthreads();
      #pragma unroll
      for (int p = 0; p < 2; ++p) {
        bf16x8 af[2], bfr[2];
        #pragma unroll
        for (int i = 0; i < 2; ++i)
          af[i] = *(const bf16x8*)&Asl[p * 2048 + (wm2 + i * 16 + l15) * 32 + quad * 8];
        #pragma unroll
        for (int j = 0; j < 2; ++j)
          bfr[j] = *(const bf16x8*)&Bsl[p * 2048 + (wn2 + j * 16 + l15) * 32 + quad * 8];
        #pragma unroll
        for (int i = 0; i < 2; ++i)
          #pragma unroll
          for (int j = 0; j < 2; ++j)
            acc[i][j] = __builtin_amdgcn_mfma_f32_16x16x32_bf16(af[i], bfr[j], acc[i][j], 0, 0, 0);
      }
    }
    const int row0 = i0 + wm2 + quad * 4;
    const int col0 = j0 + wn2 + l15;
    #pragma unroll
    for (int i = 0; i < 2; ++i)
      #pragma unroll
      for (int j = 0; j < 2; ++j)
        #pragma unroll
        for (int r = 0; r < 4; ++r)
          G[(size_t)(row0 + i * 16 + r) * 1024 + (col0 + j * 16)] = f2bf(acc[i][j][r]);
    return;
  }

  // ---- gemm1: Hexp[8192,4096] = xq @ Wq (2048 blocks, l = bidx-256) ----
  // 256 % 8 == 0 so l%8 still matches the HW XCD round-robin.
  const int l = bidx - 256;
  const int xcd = l & 7;
  const int s = l >> 3;                     // 0..255
  const int t = (xcd << 2) | (s >> 6);      // 0..31
  const int u = s & 63;
  const int bx = ((t & 3) << 3) | (u & 7);  // 0..31
  const int by = ((t >> 2) << 3) | (u >> 3);// 0..63

  const int wm = (wave >> 1) << 6, wn = (wave & 1) << 6;

  const ushort* Ag = Aq + (size_t)(by * 128 + (tid >> 2)) * 1024 + (tid & 3) * 8;
  const ushort* Bg = BT + (size_t)(bx * 128 + (tid >> 2)) * 1024 + (tid & 3) * 8;
  ushort* Asl0 = As[0] + tid * 8; ushort* Asl1 = As[1] + tid * 8;
  ushort* Bsl0 = Bs[0] + tid * 8; ushort* Bsl1 = Bs[1] + tid * 8;

  f32x4 acc[4][4];
  #pragma unroll
  for (int i = 0; i < 4; ++i)
    #pragma unroll
    for (int j = 0; j < 4; ++j) acc[i][j] = (f32x4){0.f, 0.f, 0.f, 0.f};

  for (int k0 = 0; k0 < 1024; k0 += 64) {
    __syncthreads();
    gload16(Ag + k0, Asl0);
    gload16(Ag + 64 * 1024 + k0, Asl0 + 64 * 32);
    gload16(Bg + k0, Bsl0);
    gload16(Bg + 64 * 1024 + k0, Bsl0 + 64 * 32);
    gload16(Ag + k0 + 32, Asl1);
    gload16(Ag + 64 * 1024 + k0 + 32, Asl1 + 64 * 32);
    gload16(Bg + k0 + 32, Bsl1);
    gload16(Bg + 64 * 1024 + k0 + 32, Bsl1 + 64 * 32);
    __syncthreads();

    #pragma unroll
    for (int p = 0; p < 2; ++p) {
      bf16x8 af[4], bfr[4];
      #pragma unroll
      for (int i = 0; i < 4; ++i)
        af[i] = *(const bf16x8*)&As[p][(wm + i * 16 + l15) * 32 + quad * 8];
      #pragma unroll
      for (int j = 0; j < 4; ++j)
        bfr[j] = *(const bf16x8*)&Bs[p][(wn + j * 16 + l15) * 32 + quad * 8];
      #pragma unroll
      for (int i = 0; i < 4; ++i)
        #pragma unroll
        for (int j = 0; j < 4; ++j)
          acc[i][j] = __builtin_amdgcn_mfma_f32_16x16x32_bf16(af[i], bfr[j], acc[i][j], 0, 0, 0);
    }
  }

  const int row0 = by * 128 + wm + quad * 4;
  const int col0 = bx * 128 + wn + l15;
  float lmax = 0.f;
  #pragma unroll
  for (int i = 0; i < 4; ++i)
    #pragma unroll
    for (int j = 0; j < 4; ++j)
      #pragma unroll
      for (int r = 0; r < 4; ++r) {
        float v = acc[i][j][r];
        lmax = fmaxf(lmax, fabsf(v));
        Hexp[(size_t)(row0 + i * 16 + r) * 4096 + (col0 + j * 16)] = f2bf(v);
      }

  #pragma unroll
  for (int off = 32; off > 0; off >>= 1)
    lmax = fmaxf(lmax, __shfl_down(lmax, off));
  if (lane == 0) wredmax[wave] = lmax;
  __syncthreads();
  if (tid == 0) {
    float m = fmaxf(fmaxf(wredmax[0], wredmax[1]), fmaxf(wredmax[2], wredmax[3]));
    atomicMax(amax_bits, __float_as_uint(m));
  }
}

// ---------------- quantize Hexp [8192,4096] in place (16B accesses) ----------------
__global__ void quant_h_kernel(ushort* __restrict__ H,
                               const unsigned* __restrict__ amax_bits) {
  const float amax = fmaxf(__uint_as_float(*amax_bits), 1e-8f);
  const float scale = 127.f / amax;
  const int n8 = 8192 * 4096 / 8;  // uint4 chunks (contiguous array)
  for (int i = blockIdx.x * blockDim.x + threadIdx.x; i < n8;
       i += gridDim.x * blockDim.x) {
    uint4* p = (uint4*)H + i;
    uint4 a = *p;
    unsigned w[4] = {a.x, a.y, a.z, a.w};
    #pragma unroll
    for (int j = 0; j < 4; ++j) {
      float lo = bf2f((ushort)(w[j] & 0xFFFF));
      float hi = bf2f((ushort)(w[j] >> 16));
      lo = fminf(fmaxf(rintf(lo * scale), -128.f), 127.f) / scale;
      hi = fminf(fmaxf(rintf(hi * scale), -128.f), 127.f) / scale;
      w[j] = (unsigned)f2bf(lo) | ((unsigned)f2bf(hi) << 16);
    }
    *p = make_uint4(w[0], w[1], w[2], w[3]);
  }
}

// ---------------- GEMM2: out[8192,1024] = relu(Hq@Wq^T + xbf@G + b) ----------------
// Split-K: loop1 K=4096 (Hq, Wq B^T-layout), loop2 K=1024 (xbf, G symmetric).
// 512 blocks; XCD swizzle: each XCD owns 8 consecutive by row-tiles.
__global__ __launch_bounds__(256, 2) void gemm2_kernel(
    const ushort* __restrict__ Hq, const ushort* __restrict__ Wq,
    const ushort* __restrict__ Xb, const ushort* __restrict__ G,
    const float* __restrict__ bias, float* __restrict__ out) {
  __shared__ __align__(16) ushort As[2][128 * 32];
  __shared__ __align__(16) ushort Bs[2][128 * 32];

  const int l = blockIdx.x;
  const int xcd = l & 7;
  const int s = l >> 3;
  const int by = (xcd << 3) | (s >> 3);
  const int bx = s & 7;

  const int tid = threadIdx.x;
  const int lane = tid & 63, wave = tid >> 6;
  const int wm = (wave >> 1) << 6, wn = (wave & 1) << 6;
  const int l15 = lane & 15, quad = lane >> 4;

  ushort* Asl0 = As[0] + tid * 8; ushort* Asl1 = As[1] + tid * 8;
  ushort* Bsl0 = Bs[0] + tid * 8; ushort* Bsl1 = Bs[1] + tid * 8;

  f32x4 acc[4][4];
  #pragma unroll
  for (int i = 0; i < 4; ++i)
    #pragma unroll
    for (int j = 0; j < 4; ++j) acc[i][j] = (f32x4){0.f, 0.f, 0.f, 0.f};

  // ---- loop 1: K=4096 over Hq / Wq (stride 4096) ----
  {
    const ushort* Ag = Hq + (size_t)(by * 128 + (tid >> 2)) * 4096 + (tid & 3) * 8;
    const ushort* Bg = Wq + (size_t)(bx * 128 + (tid >> 2)) * 4096 + (tid & 3) * 8;
    for (int k0 = 0; k0 < 4096; k0 += 64) {
      __syncthreads();
      gload16(Ag + k0, Asl0);
      gload16(Ag + (size_t)64 * 4096 + k0, Asl0 + 64 * 32);
      gload16(Bg + k0, Bsl0);
      gload16(Bg + (size_t)64 * 4096 + k0, Bsl0 + 64 * 32);
      gload16(Ag + k0 + 32, Asl1);
      gload16(Ag + (size_t)64 * 4096 + k0 + 32, Asl1 + 64 * 32);
      gload16(Bg + k0 + 32, Bsl1);
      gload16(Bg + (size_t)64 * 4096 + k0 + 32, Bsl1 + 64 * 32);
      __syncthreads();
      #pragma unroll
      for (int p = 0; p < 2; ++p) {
        bf16x8 af[4], bfr[4];
        #pragma unroll
        for (int i = 0; i < 4; ++i)
          af[i] = *(const bf16x8*)&As[p][(wm + i * 16 + l15) * 32 + quad * 8];
        #pragma unroll
        for (int j = 0; j < 4; ++j)
          bfr[j] = *(const bf16x8*)&Bs[p][(wn + j * 16 + l15) * 32 + quad * 8];
        #pragma unroll
        for (int i = 0; i < 4; ++i)
          #pragma unroll
          for (int j = 0; j < 4; ++j)
            acc[i][j] = __builtin_amdgcn_mfma_f32_16x16x32_bf16(af[i], bfr[j], acc[i][j], 0, 0, 0);
      }
    }
  }
  // ---- loop 2: K=1024 over xbf / G (stride 1024) ----
  {
    const ushort* Ag = Xb + (size_t)(by * 128 + (tid >> 2)) * 1024 + (tid & 3) * 8;
    const ushort* Bg = G + (size_t)(bx * 128 + (tid >> 2)) * 1024 + (tid & 3) * 8;
    for (int k0 = 0; k0 < 1024; k0 += 64) {
      __syncthreads();
      gload16(Ag + k0, Asl0);
      gload16(Ag + 64 * 1024 + k0, Asl0 + 64 * 32);
      gload16(Bg + k0, Bsl0);
      gload16(Bg + 64 * 1024 + k0, Bsl0 + 64 * 32);
      gload16(Ag + k0 + 32, Asl1);
      gload16(Ag + 64 * 1024 + k0 + 32, Asl1 + 64 * 32);
      gload16(Bg + k0 + 32, Bsl1);
      gload16(Bg + 64 * 1024 + k0 + 32, Bsl1 + 64 * 32);
      __syncthreads();
      #pragma unroll
      for (int p = 0; p < 2; ++p) {
        bf16x8 af[4], bfr[4];
        #pragma unroll
        for (int i = 0; i < 4; ++i)
          af[i] = *(const bf16x8*)&As[p][(wm + i * 16 + l15) * 32 + quad * 8];
        #pragma unroll
        for (int j = 0; j < 4; ++j)
          bfr[j] = *(const bf16x8*)&Bs[p][(wn + j * 16 + l15) * 32 + quad * 8];
        #pragma unroll
        for (int i = 0; i < 4; ++i)
          #pragma unroll
          for (int j = 0; j < 4; ++j)
            acc[i][j] = __builtin_amdgcn_mfma_f32_16x16x32_bf16(af[i], bfr[j], acc[i][j], 0, 0, 0);
      }
    }
  }

  const int row0 = by * 128 + wm + quad * 4;
  const int col0 = bx * 128 + wn + l15;
  #pragma unroll
  for (int i = 0; i < 4; ++i)
    #pragma unroll
    for (int j = 0; j < 4; ++j) {
      float bv = bias[col0 + j * 16];
      #pragma unroll
      for (int r = 0; r < 4; ++r) {
        float v = acc[i][j][r] + bv;
        v = fmaxf(v, 0.f);
        out[(size_t)(row0 + i * 16 + r) * 1024 + (col0 + j * 16)] = v;
      }
    }
}

extern "C" void kernel_launch(void* const* d_in, const int* in_sizes, int n_in,
                              void* d_out, int out_size, void* d_ws, size_t ws_size,
                              hipStream_t stream) {
  (void)in_sizes; (void)n_in; (void)out_size; (void)ws_size;
  const float* x = (const float*)d_in[0];   // [8192,1024]
  const float* W = (const float*)d_in[1];   // [1024,8192]
  const float* b = (const float*)d_in[2];   // [1024]

  char* ws = (char*)d_ws;
  unsigned* scal = (unsigned*)ws;                      // [0]=amax_x, [1]=amax_h
  ushort* xq   = (ushort*)(ws + 256);                  // 16 MB [8192,1024]
  ushort* xbf  = xq   + (size_t)8192 * 1024;           // 16 MB [8192,1024]
  ushort* Wq   = xbf  + (size_t)8192 * 1024;           //  8 MB [1024,4096]
  ushort* WqT  = Wq   + (size_t)1024 * 4096;           //  8 MB [4096,1024]
  ushort* Wcb  = WqT  + (size_t)4096 * 1024;           //  8 MB [1024,4096]
  ushort* G    = Wcb  + (size_t)1024 * 4096;           //  2 MB [1024,1024]
  ushort* Hexp = G    + (size_t)1024 * 1024;           // 64 MB [8192,4096]

  hipMemsetAsync(scal, 0, 256, stream);  // ws is re-poisoned 0xAA before every call
  // L1: W-quant (16384 blocks) | Wc-cast (4096) | amax_x (2048)
  prep_wa_kernel<<<22528, 256, 0, stream>>>(W, (const float4*)x, Wq, Wcb, scal);
  // L2: transpose (1024) | prep_x (2048)
  prep_xt_kernel<<<3072, 256, 0, stream>>>(Wq, WqT, (const float4*)x, scal,
                                           (uint4*)xq, (uint4*)xbf);
  // L3: G-GEMM (256, reads Wcb) | gemm1 (2048)
  gemm1_kernel<<<2304, 256, 0, stream>>>(Wcb, G, xq, WqT, Hexp, scal + 1);
  quant_h_kernel<<<2048, 256, 0, stream>>>(Hexp, scal + 1);
  gemm2_kernel<<<512, 256, 0, stream>>>(Hexp, Wq, xbf, G, b, (float*)d_out);
}

// Round 11
// 344.251 us; speedup vs baseline: 1.7292x; 1.0409x over previous
//
#include <hip/hip_runtime.h>
#include <hip/hip_bf16.h>
#include <cstdint>

// Problem constants: W [N=1024, M=8192], x [B=8192, N=1024], b [1024]
// idx = 0..4095 (quantized cols), idx_comp = 4096..8191 (continuous cols)
//
// cont path = x @ (Wc@Wc^T) = x @ G, G [1024,1024] symmetric.
// DAG (all bf16 MFMA):
//   L1: W-quant+transpose -> Wq,WqT (blocks<1024) | Wc cast -> Wcb (<5120) | amax_x
//   L2: prep_x (xq, xbf)
//   L3: G = Wcb@Wcb^T (128x128 tiles, blocks<64) | gemm1: Hexp = xq@Wq + amax_h
//   L4: quant_h in place
//   L5: gemm2: out = relu(Hq@Wq^T + xbf@G + b)   (split-K: 4096 + 1024)

using bf16x8 = __attribute__((ext_vector_type(8))) __bf16;
using f32x4  = __attribute__((ext_vector_type(4))) float;

typedef const __attribute__((address_space(1))) void g_void;
typedef __attribute__((address_space(3))) void l_void;

__device__ __forceinline__ void gload16(const void* g, void* l) {
  __builtin_amdgcn_global_load_lds((g_void*)g, (l_void*)l, 16, 0, 0);
}

__device__ __forceinline__ ushort f2bf(float f) {
  union { float f; unsigned u; } c; c.f = f;
  unsigned r = c.u + 0x7FFFu + ((c.u >> 16) & 1u);  // RNE truncate
  return (ushort)(r >> 16);
}
__device__ __forceinline__ float bf2f(ushort u) {
  union { unsigned u; float f; } c; c.u = ((unsigned)u) << 16;
  return c.f;
}

// ============ L1: W quant+transpose (blocks <1024) | Wc cast (<5120) | amax_x ============
__global__ void prep_wa_kernel(const float* __restrict__ W,
                               const float4* __restrict__ x,
                               ushort* __restrict__ Wq,
                               ushort* __restrict__ WqT,
                               ushort* __restrict__ Wcb,
                               unsigned* __restrict__ amax_bits) {
  const int bidx = blockIdx.x;
  const int tid = threadIdx.x;

  if (bidx < 1024) {
    // ---- quantize a 64x64 tile of W[:, :4096]; write Wq + WqT (LDS transpose) ----
    __shared__ __align__(16) ushort tile[64][72];  // [col][row], pad 72: rows 16B-aligned
    const int rt = bidx >> 6;         // 16 row tiles (1024/64)
    const int ct = bidx & 63;         // 64 col tiles (4096/64)
    const int r0 = rt * 64, c0 = ct * 64;
    const int e = tid & 31;           // element within 32-quant-block
    const int hw = tid >> 5;          // half-wave id 0..7
    #pragma unroll
    for (int it = 0; it < 16; ++it) {
      const int g = it * 8 + hw;      // 0..127 quant-groups in tile
      const int row = g >> 1;
      const int cg = (g & 1) * 32;
      const float w = W[(size_t)(r0 + row) * 8192 + c0 + cg + e];
      float aw = fabsf(w);
      float m = aw;
      #pragma unroll
      for (int d = 1; d <= 16; d <<= 1) m = fmaxf(m, __shfl_xor(m, d));
      int idx = (aw == m) ? e : 32;
      #pragma unroll
      for (int d = 1; d <= 16; d <<= 1) idx = min(idx, __shfl_xor(idx, d));
      const int i1 = idx;
      float a2 = (e == i1) ? -1.f : aw;
      float m2 = a2;
      #pragma unroll
      for (int d = 1; d <= 16; d <<= 1) m2 = fmaxf(m2, __shfl_xor(m2, d));
      int idx2 = (a2 == m2) ? e : 32;
      #pragma unroll
      for (int d = 1; d <= 16; d <<= 1) idx2 = min(idx2, __shfl_xor(idx2, d));
      const int i2 = idx2;

      const float scale = fmaxf(m, 1e-8f);
      const float nb = w / scale;
      float q;
      if (e == i1 || e == i2) {
        q = rintf(nb * 7.f) / 7.f;
      } else {
        float s = (nb > 0.f) ? 1.f : ((nb < 0.f) ? -1.f : 0.f);
        q = s * ((fabsf(nb) > 0.66f) ? 1.f : (1.f / 3.f));
      }
      const ushort qb = f2bf(q * scale);
      Wq[(size_t)(r0 + row) * 4096 + c0 + cg + e] = qb;
      tile[cg + e][row] = qb;
    }
    __syncthreads();
    // transposed write: WqT row (c0+c) gets tile[c][0..64) at offset r0
    const int c = tid >> 2;
    const int q4 = (tid & 3) * 16;
    uint4 v0 = *(const uint4*)&tile[c][q4];
    uint4 v1 = *(const uint4*)&tile[c][q4 + 8];
    *(uint4*)(WqT + (size_t)(c0 + c) * 1024 + r0 + q4) = v0;
    *(uint4*)(WqT + (size_t)(c0 + c) * 1024 + r0 + q4 + 8) = v1;
  } else if (bidx < 5120) {
    // ---- cast W[:, 4096:] to bf16 -> Wcb [1024,4096] ----
    const int u = (bidx - 1024) * 256 + tid;   // 0 .. 1024*1024-1
    const int row = u >> 10;
    const int c4 = u & 1023;
    float4 v = *(const float4*)(W + (size_t)row * 8192 + 4096 + c4 * 4);
    ushort4 o;
    o.x = f2bf(v.x); o.y = f2bf(v.y); o.z = f2bf(v.z); o.w = f2bf(v.w);
    *(ushort4*)(Wcb + (size_t)row * 4096 + c4 * 4) = o;
  } else {
    // ---- amax(|x|) ----
    float m = 0.f;
    const int base = (bidx - 5120) * 256 + tid;
    const int stride = 2048 * 256;
    for (int i = base; i < 8192 * 1024 / 4; i += stride) {
      float4 v = x[i];
      m = fmaxf(m, fmaxf(fmaxf(fabsf(v.x), fabsf(v.y)),
                         fmaxf(fabsf(v.z), fabsf(v.w))));
    }
    #pragma unroll
    for (int off = 32; off > 0; off >>= 1) m = fmaxf(m, __shfl_down(m, off));
    __shared__ float wm[4];
    int lane = tid & 63, wave = tid >> 6;
    if (lane == 0) wm[wave] = m;
    __syncthreads();
    if (tid == 0) {
      float r = fmaxf(fmaxf(wm[0], wm[1]), fmaxf(wm[2], wm[3]));
      atomicMax(amax_bits, __float_as_uint(r));
    }
  }
}

// ============ L2: prep_x (xq fake-quant + xbf cast), 16B stores ============
__global__ void prep_x_kernel(const float4* __restrict__ x,
                              const unsigned* __restrict__ amax_bits,
                              uint4* __restrict__ xq, uint4* __restrict__ xbf) {
  const float amax = fmaxf(__uint_as_float(*amax_bits), 1e-8f);
  const float scale = 127.f / amax;
  const int base = blockIdx.x * 256 + threadIdx.x;
  const int stride = 2048 * 256;
  const int n8 = 8192 * 1024 / 8;
  for (int i = base; i < n8; i += stride) {
    float4 a = x[i * 2], b = x[i * 2 + 1];
    float v[8] = {a.x, a.y, a.z, a.w, b.x, b.y, b.z, b.w};
    unsigned qw[4], bw[4];
    #pragma unroll
    for (int j = 0; j < 4; ++j) {
      float q0 = fminf(fmaxf(rintf(v[2 * j] * scale), -128.f), 127.f) / scale;
      float q1 = fminf(fmaxf(rintf(v[2 * j + 1] * scale), -128.f), 127.f) / scale;
      qw[j] = (unsigned)f2bf(q0) | ((unsigned)f2bf(q1) << 16);
      bw[j] = (unsigned)f2bf(v[2 * j]) | ((unsigned)f2bf(v[2 * j + 1]) << 16);
    }
    xq[i] = make_uint4(qw[0], qw[1], qw[2], qw[3]);
    xbf[i] = make_uint4(bw[0], bw[1], bw[2], bw[3]);
  }
}

// ============ L3: G-GEMM 128x128 tiles (blocks <64) | gemm1 ============
// G[i,j] = sum_m Wcb[i,m]*Wcb[j,m] — gemm2-loop1-style staging, stride 4096.
__global__ __launch_bounds__(256, 2) void gemm1_kernel(
    const ushort* __restrict__ Wcb,
    ushort* __restrict__ G,
    const ushort* __restrict__ Aq, const ushort* __restrict__ BT,
    ushort* __restrict__ Hexp, unsigned* __restrict__ amax_bits) {
  __shared__ __align__(16) ushort As[2][128 * 32];
  __shared__ __align__(16) ushort Bs[2][128 * 32];
  __shared__ float wredmax[4];

  const int bidx = blockIdx.x;
  const int tid = threadIdx.x;
  const int lane = tid & 63, wave = tid >> 6;
  const int l15 = lane & 15, quad = lane >> 4;
  const int wm = (wave >> 1) << 6, wn = (wave & 1) << 6;

  ushort* Asl0 = As[0] + tid * 8; ushort* Asl1 = As[1] + tid * 8;
  ushort* Bsl0 = Bs[0] + tid * 8; ushort* Bsl1 = Bs[1] + tid * 8;

  f32x4 acc[4][4];
  #pragma unroll
  for (int i = 0; i < 4; ++i)
    #pragma unroll
    for (int j = 0; j < 4; ++j) acc[i][j] = (f32x4){0.f, 0.f, 0.f, 0.f};

  if (bidx < 64) {
    // ---- G-GEMM: 128x128 tile per block, K=4096 ----
    const int gy = bidx >> 3, gx = bidx & 7;
    const int i0 = gy * 128, j0 = gx * 128;
    const ushort* Ag = Wcb + (size_t)(i0 + (tid >> 2)) * 4096 + (tid & 3) * 8;
    const ushort* Bg = Wcb + (size_t)(j0 + (tid >> 2)) * 4096 + (tid & 3) * 8;
    for (int k0 = 0; k0 < 4096; k0 += 64) {
      __syncthreads();
      gload16(Ag + k0, Asl0);
      gload16(Ag + (size_t)64 * 4096 + k0, Asl0 + 64 * 32);
      gload16(Bg + k0, Bsl0);
      gload16(Bg + (size_t)64 * 4096 + k0, Bsl0 + 64 * 32);
      gload16(Ag + k0 + 32, Asl1);
      gload16(Ag + (size_t)64 * 4096 + k0 + 32, Asl1 + 64 * 32);
      gload16(Bg + k0 + 32, Bsl1);
      gload16(Bg + (size_t)64 * 4096 + k0 + 32, Bsl1 + 64 * 32);
      __syncthreads();
      #pragma unroll
      for (int p = 0; p < 2; ++p) {
        bf16x8 af[4], bfr[4];
        #pragma unroll
        for (int i = 0; i < 4; ++i)
          af[i] = *(const bf16x8*)&As[p][(wm + i * 16 + l15) * 32 + quad * 8];
        #pragma unroll
        for (int j = 0; j < 4; ++j)
          bfr[j] = *(const bf16x8*)&Bs[p][(wn + j * 16 + l15) * 32 + quad * 8];
        #pragma unroll
        for (int i = 0; i < 4; ++i)
          #pragma unroll
          for (int j = 0; j < 4; ++j)
            acc[i][j] = __builtin_amdgcn_mfma_f32_16x16x32_bf16(af[i], bfr[j], acc[i][j], 0, 0, 0);
      }
    }
    const int row0 = i0 + wm + quad * 4;
    const int col0 = j0 + wn + l15;
    #pragma unroll
    for (int i = 0; i < 4; ++i)
      #pragma unroll
      for (int j = 0; j < 4; ++j)
        #pragma unroll
        for (int r = 0; r < 4; ++r)
          G[(size_t)(row0 + i * 16 + r) * 1024 + (col0 + j * 16)] = f2bf(acc[i][j][r]);
    return;
  }

  // ---- gemm1: Hexp[8192,4096] = xq @ Wq (2048 blocks, l = bidx-64) ----
  // 64 % 8 == 0 so l%8 still matches the HW XCD round-robin.
  const int l = bidx - 64;
  const int xcd = l & 7;
  const int s = l >> 3;                     // 0..255
  const int t = (xcd << 2) | (s >> 6);      // 0..31
  const int u = s & 63;
  const int bx = ((t & 3) << 3) | (u & 7);  // 0..31
  const int by = ((t >> 2) << 3) | (u >> 3);// 0..63

  const ushort* Ag = Aq + (size_t)(by * 128 + (tid >> 2)) * 1024 + (tid & 3) * 8;
  const ushort* Bg = BT + (size_t)(bx * 128 + (tid >> 2)) * 1024 + (tid & 3) * 8;

  for (int k0 = 0; k0 < 1024; k0 += 64) {
    __syncthreads();
    gload16(Ag + k0, Asl0);
    gload16(Ag + 64 * 1024 + k0, Asl0 + 64 * 32);
    gload16(Bg + k0, Bsl0);
    gload16(Bg + 64 * 1024 + k0, Bsl0 + 64 * 32);
    gload16(Ag + k0 + 32, Asl1);
    gload16(Ag + 64 * 1024 + k0 + 32, Asl1 + 64 * 32);
    gload16(Bg + k0 + 32, Bsl1);
    gload16(Bg + 64 * 1024 + k0 + 32, Bsl1 + 64 * 32);
    __syncthreads();

    #pragma unroll
    for (int p = 0; p < 2; ++p) {
      bf16x8 af[4], bfr[4];
      #pragma unroll
      for (int i = 0; i < 4; ++i)
        af[i] = *(const bf16x8*)&As[p][(wm + i * 16 + l15) * 32 + quad * 8];
      #pragma unroll
      for (int j = 0; j < 4; ++j)
        bfr[j] = *(const bf16x8*)&Bs[p][(wn + j * 16 + l15) * 32 + quad * 8];
      #pragma unroll
      for (int i = 0; i < 4; ++i)
        #pragma unroll
        for (int j = 0; j < 4; ++j)
          acc[i][j] = __builtin_amdgcn_mfma_f32_16x16x32_bf16(af[i], bfr[j], acc[i][j], 0, 0, 0);
    }
  }

  const int row0 = by * 128 + wm + quad * 4;
  const int col0 = bx * 128 + wn + l15;
  float lmax = 0.f;
  #pragma unroll
  for (int i = 0; i < 4; ++i)
    #pragma unroll
    for (int j = 0; j < 4; ++j)
      #pragma unroll
      for (int r = 0; r < 4; ++r) {
        float v = acc[i][j][r];
        lmax = fmaxf(lmax, fabsf(v));
        Hexp[(size_t)(row0 + i * 16 + r) * 4096 + (col0 + j * 16)] = f2bf(v);
      }

  #pragma unroll
  for (int off = 32; off > 0; off >>= 1)
    lmax = fmaxf(lmax, __shfl_down(lmax, off));
  if (lane == 0) wredmax[wave] = lmax;
  __syncthreads();
  if (tid == 0) {
    float m = fmaxf(fmaxf(wredmax[0], wredmax[1]), fmaxf(wredmax[2], wredmax[3]));
    atomicMax(amax_bits, __float_as_uint(m));
  }
}

// ---------------- quantize Hexp [8192,4096] in place (16B accesses) ----------------
__global__ void quant_h_kernel(ushort* __restrict__ H,
                               const unsigned* __restrict__ amax_bits) {
  const float amax = fmaxf(__uint_as_float(*amax_bits), 1e-8f);
  const float scale = 127.f / amax;
  const int n8 = 8192 * 4096 / 8;  // uint4 chunks (contiguous array)
  for (int i = blockIdx.x * blockDim.x + threadIdx.x; i < n8;
       i += gridDim.x * blockDim.x) {
    uint4* p = (uint4*)H + i;
    uint4 a = *p;
    unsigned w[4] = {a.x, a.y, a.z, a.w};
    #pragma unroll
    for (int j = 0; j < 4; ++j) {
      float lo = bf2f((ushort)(w[j] & 0xFFFF));
      float hi = bf2f((ushort)(w[j] >> 16));
      lo = fminf(fmaxf(rintf(lo * scale), -128.f), 127.f) / scale;
      hi = fminf(fmaxf(rintf(hi * scale), -128.f), 127.f) / scale;
      w[j] = (unsigned)f2bf(lo) | ((unsigned)f2bf(hi) << 16);
    }
    *p = make_uint4(w[0], w[1], w[2], w[3]);
  }
}

// ---------------- GEMM2: out[8192,1024] = relu(Hq@Wq^T + xbf@G + b) ----------------
// Split-K: loop1 K=4096 (Hq, Wq B^T-layout), loop2 K=1024 (xbf, G symmetric).
// 512 blocks; XCD swizzle: each XCD owns 8 consecutive by row-tiles.
__global__ __launch_bounds__(256, 2) void gemm2_kernel(
    const ushort* __restrict__ Hq, const ushort* __restrict__ Wq,
    const ushort* __restrict__ Xb, const ushort* __restrict__ G,
    const float* __restrict__ bias, float* __restrict__ out) {
  __shared__ __align__(16) ushort As[2][128 * 32];
  __shared__ __align__(16) ushort Bs[2][128 * 32];

  const int l = blockIdx.x;
  const int xcd = l & 7;
  const int s = l >> 3;
  const int by = (xcd << 3) | (s >> 3);
  const int bx = s & 7;

  const int tid = threadIdx.x;
  const int lane = tid & 63, wave = tid >> 6;
  const int wm = (wave >> 1) << 6, wn = (wave & 1) << 6;
  const int l15 = lane & 15, quad = lane >> 4;

  ushort* Asl0 = As[0] + tid * 8; ushort* Asl1 = As[1] + tid * 8;
  ushort* Bsl0 = Bs[0] + tid * 8; ushort* Bsl1 = Bs[1] + tid * 8;

  f32x4 acc[4][4];
  #pragma unroll
  for (int i = 0; i < 4; ++i)
    #pragma unroll
    for (int j = 0; j < 4; ++j) acc[i][j] = (f32x4){0.f, 0.f, 0.f, 0.f};

  // ---- loop 1: K=4096 over Hq / Wq (stride 4096) ----
  {
    const ushort* Ag = Hq + (size_t)(by * 128 + (tid >> 2)) * 4096 + (tid & 3) * 8;
    const ushort* Bg = Wq + (size_t)(bx * 128 + (tid >> 2)) * 4096 + (tid & 3) * 8;
    for (int k0 = 0; k0 < 4096; k0 += 64) {
      __syncthreads();
      gload16(Ag + k0, Asl0);
      gload16(Ag + (size_t)64 * 4096 + k0, Asl0 + 64 * 32);
      gload16(Bg + k0, Bsl0);
      gload16(Bg + (size_t)64 * 4096 + k0, Bsl0 + 64 * 32);
      gload16(Ag + k0 + 32, Asl1);
      gload16(Ag + (size_t)64 * 4096 + k0 + 32, Asl1 + 64 * 32);
      gload16(Bg + k0 + 32, Bsl1);
      gload16(Bg + (size_t)64 * 4096 + k0 + 32, Bsl1 + 64 * 32);
      __syncthreads();
      #pragma unroll
      for (int p = 0; p < 2; ++p) {
        bf16x8 af[4], bfr[4];
        #pragma unroll
        for (int i = 0; i < 4; ++i)
          af[i] = *(const bf16x8*)&As[p][(wm + i * 16 + l15) * 32 + quad * 8];
        #pragma unroll
        for (int j = 0; j < 4; ++j)
          bfr[j] = *(const bf16x8*)&Bs[p][(wn + j * 16 + l15) * 32 + quad * 8];
        #pragma unroll
        for (int i = 0; i < 4; ++i)
          #pragma unroll
          for (int j = 0; j < 4; ++j)
            acc[i][j] = __builtin_amdgcn_mfma_f32_16x16x32_bf16(af[i], bfr[j], acc[i][j], 0, 0, 0);
      }
    }
  }
  // ---- loop 2: K=1024 over xbf / G (stride 1024) ----
  {
    const ushort* Ag = Xb + (size_t)(by * 128 + (tid >> 2)) * 1024 + (tid & 3) * 8;
    const ushort* Bg = G + (size_t)(bx * 128 + (tid >> 2)) * 1024 + (tid & 3) * 8;
    for (int k0 = 0; k0 < 1024; k0 += 64) {
      __syncthreads();
      gload16(Ag + k0, Asl0);
      gload16(Ag + 64 * 1024 + k0, Asl0 + 64 * 32);
      gload16(Bg + k0, Bsl0);
      gload16(Bg + 64 * 1024 + k0, Bsl0 + 64 * 32);
      gload16(Ag + k0 + 32, Asl1);
      gload16(Ag + 64 * 1024 + k0 + 32, Asl1 + 64 * 32);
      gload16(Bg + k0 + 32, Bsl1);
      gload16(Bg + 64 * 1024 + k0 + 32, Bsl1 + 64 * 32);
      __syncthreads();
      #pragma unroll
      for (int p = 0; p < 2; ++p) {
        bf16x8 af[4], bfr[4];
        #pragma unroll
        for (int i = 0; i < 4; ++i)
          af[i] = *(const bf16x8*)&As[p][(wm + i * 16 + l15) * 32 + quad * 8];
        #pragma unroll
        for (int j = 0; j < 4; ++j)
          bfr[j] = *(const bf16x8*)&Bs[p][(wn + j * 16 + l15) * 32 + quad * 8];
        #pragma unroll
        for (int i = 0; i < 4; ++i)
          #pragma unroll
          for (int j = 0; j < 4; ++j)
            acc[i][j] = __builtin_amdgcn_mfma_f32_16x16x32_bf16(af[i], bfr[j], acc[i][j], 0, 0, 0);
      }
    }
  }

  const int row0 = by * 128 + wm + quad * 4;
  const int col0 = bx * 128 + wn + l15;
  #pragma unroll
  for (int i = 0; i < 4; ++i)
    #pragma unroll
    for (int j = 0; j < 4; ++j) {
      float bv = bias[col0 + j * 16];
      #pragma unroll
      for (int r = 0; r < 4; ++r) {
        float v = acc[i][j][r] + bv;
        v = fmaxf(v, 0.f);
        out[(size_t)(row0 + i * 16 + r) * 1024 + (col0 + j * 16)] = v;
      }
    }
}

extern "C" void kernel_launch(void* const* d_in, const int* in_sizes, int n_in,
                              void* d_out, int out_size, void* d_ws, size_t ws_size,
                              hipStream_t stream) {
  (void)in_sizes; (void)n_in; (void)out_size; (void)ws_size;
  const float* x = (const float*)d_in[0];   // [8192,1024]
  const float* W = (const float*)d_in[1];   // [1024,8192]
  const float* b = (const float*)d_in[2];   // [1024]

  char* ws = (char*)d_ws;
  unsigned* scal = (unsigned*)ws;                      // [0]=amax_x, [1]=amax_h
  ushort* xq   = (ushort*)(ws + 256);                  // 16 MB [8192,1024]
  ushort* xbf  = xq   + (size_t)8192 * 1024;           // 16 MB [8192,1024]
  ushort* Wq   = xbf  + (size_t)8192 * 1024;           //  8 MB [1024,4096]
  ushort* WqT  = Wq   + (size_t)1024 * 4096;           //  8 MB [4096,1024]
  ushort* Wcb  = WqT  + (size_t)4096 * 1024;           //  8 MB [1024,4096]
  ushort* G    = Wcb  + (size_t)1024 * 4096;           //  2 MB [1024,1024]
  ushort* Hexp = G    + (size_t)1024 * 1024;           // 64 MB [8192,4096]

  hipMemsetAsync(scal, 0, 256, stream);  // ws is re-poisoned 0xAA before every call
  // L1: W-quant+transpose (1024 blocks) | Wc-cast (4096) | amax_x (2048)
  prep_wa_kernel<<<7168, 256, 0, stream>>>(W, (const float4*)x, Wq, WqT, Wcb, scal);
  // L2: prep_x (2048)
  prep_x_kernel<<<2048, 256, 0, stream>>>((const float4*)x, scal,
                                          (uint4*)xq, (uint4*)xbf);
  // L3: G-GEMM (64 blocks, 128x128 tiles) | gemm1 (2048)
  gemm1_kernel<<<2112, 256, 0, stream>>>(Wcb, G, xq, WqT, Hexp, scal + 1);
  quant_h_kernel<<<4096, 256, 0, stream>>>(Hexp, scal + 1);
  gemm2_kernel<<<512, 256, 0, stream>>>(Hexp, Wq, xbf, G, b, (float*)d_out);
}